// Round 1
// baseline (888.796 us; speedup 1.0000x reference)
//
#include <hip/hip_runtime.h>
#include <hip/hip_bf16.h>

typedef unsigned short u16;

#define B_   16
#define N1_  4096
#define N2_  1024
#define C1_  128
#define C2_  256
#define CIN_ 384
#define CM_  256
#define CO_  128

__device__ __forceinline__ u16 f2bf(float f) {
  unsigned u = __float_as_uint(f);
  u = (u + 0x7fffu + ((u >> 16) & 1u)) >> 16;
  return (u16)u;
}
__device__ __forceinline__ float bf2f(u16 h) {
  return __uint_as_float(((unsigned)h) << 16);
}

// ---------------- K1: 3-NN (top-3 smallest sq dists) ----------------
__global__ __launch_bounds__(256) void knn_kernel(
    const float* __restrict__ xyz1, const float* __restrict__ xyz2,
    int* __restrict__ idx_out, float* __restrict__ w_out)
{
  __shared__ float sx[N2_], sy[N2_], sz[N2_];
  int b = blockIdx.y;
  const float* p2 = xyz2 + b * N2_ * 3;
  for (int t = threadIdx.x; t < N2_; t += 256) {
    sx[t] = p2[t*3+0]; sy[t] = p2[t*3+1]; sz[t] = p2[t*3+2];
  }
  __syncthreads();
  int i = blockIdx.x * 256 + threadIdx.x;
  const float* p1 = xyz1 + (b * N1_ + i) * 3;
  float x = p1[0], y = p1[1], z = p1[2];
  float d0 = 1e30f, d1 = 1e30f, d2 = 1e30f;
  int i0 = 0, i1 = 0, i2 = 0;
  for (int j = 0; j < N2_; ++j) {
    float dx = x - sx[j], dy = y - sy[j], dz = z - sz[j];
    float d = dx*dx + dy*dy + dz*dz;
    if (d < d2) {                       // strict <: ties keep earlier index (top_k stable)
      if (d < d0)      { d2=d1; i2=i1; d1=d0; i1=i0; d0=d; i0=j; }
      else if (d < d1) { d2=d1; i2=i1; d1=d;  i1=j; }
      else             { d2=d;  i2=j; }
    }
  }
  float w0 = 1.f/(d0+1e-8f), w1 = 1.f/(d1+1e-8f), w2 = 1.f/(d2+1e-8f);
  float inv = 1.f/(w0+w1+w2);
  int base = b*N1_ + i;
  idx_out[base]            = i0;
  idx_out[base +   B_*N1_] = i1;
  idx_out[base + 2*B_*N1_] = i2;
  w_out[base]              = w0*inv;
  w_out[base +   B_*N1_]   = w1*inv;
  w_out[base + 2*B_*N1_]   = w2*inv;
}

// ---------------- K2: gather-interpolate feat2 -> interp (bf16) ----------------
__global__ __launch_bounds__(256) void interp_kernel(
    const float* __restrict__ feat2, const int* __restrict__ idx_in,
    const float* __restrict__ w_in, u16* __restrict__ interp)
{
  int b = blockIdx.y;
  int n = blockIdx.x * 256 + threadIdx.x;
  int c0 = blockIdx.z * 16;
  int base = b*N1_ + n;
  int i0 = idx_in[base], i1 = idx_in[base + B_*N1_], i2 = idx_in[base + 2*B_*N1_];
  float w0 = w_in[base], w1 = w_in[base + B_*N1_], w2 = w_in[base + 2*B_*N1_];
  const float* f2 = feat2 + (b*C2_ + c0) * N2_;
  u16* op = interp + (b*C2_ + c0) * N1_ + n;
  #pragma unroll
  for (int cc = 0; cc < 16; ++cc) {
    const float* r = f2 + cc*N2_;
    float v = w0*r[i0] + w1*r[i1] + w2*r[i2];
    op[cc*N1_] = f2bf(v);
  }
}

// ---------------- K3: GEMM1  y0 = w0 @ concat(feat1, interp) + b0, bf16 out + stats ----------------
__global__ __launch_bounds__(256) void gemm1_kernel(
    const float* __restrict__ feat1, const u16* __restrict__ interp,
    const float* __restrict__ w0p, const float* __restrict__ b0p,
    u16* __restrict__ y0, float* __restrict__ gsum, float* __restrict__ gsq)
{
  __shared__ float As[16][128];
  __shared__ float Bs[16][64];
  int b  = blockIdx.y;
  int n0 = blockIdx.x * 64;
  int o0 = blockIdx.z * 128;
  int t  = threadIdx.x;
  int tx = t & 15, ty = t >> 4;
  int ar = t >> 1, ak = (t & 1) * 8;
  int bk = t >> 4, bn = (t & 15) * 4;
  float acc[8][4] = {};
  for (int k = 0; k < CIN_; k += 16) {
    const float* wp = w0p + (o0 + ar) * CIN_ + k + ak;
    float4 av0 = *(const float4*)wp;
    float4 av1 = *(const float4*)(wp + 4);
    As[ak+0][ar] = av0.x; As[ak+1][ar] = av0.y; As[ak+2][ar] = av0.z; As[ak+3][ar] = av0.w;
    As[ak+4][ar] = av1.x; As[ak+5][ar] = av1.y; As[ak+6][ar] = av1.z; As[ak+7][ar] = av1.w;
    int c = k + bk;
    float4 bv;
    if (c < C1_) {
      bv = *(const float4*)(feat1 + (b*C1_ + c) * N1_ + n0 + bn);
    } else {
      const u16* ip = interp + (b*C2_ + (c - C1_)) * N1_ + n0 + bn;
      uint2 u = *(const uint2*)ip;
      bv.x = __uint_as_float(u.x << 16);
      bv.y = __uint_as_float(u.x & 0xffff0000u);
      bv.z = __uint_as_float(u.y << 16);
      bv.w = __uint_as_float(u.y & 0xffff0000u);
    }
    *(float4*)&Bs[bk][bn] = bv;
    __syncthreads();
    #pragma unroll
    for (int kk = 0; kk < 16; ++kk) {
      float4 a0v = *(const float4*)&As[kk][ty*8];
      float4 a1v = *(const float4*)&As[kk][ty*8+4];
      float4 bv2 = *(const float4*)&Bs[kk][tx*4];
      float aa[8] = {a0v.x,a0v.y,a0v.z,a0v.w,a1v.x,a1v.y,a1v.z,a1v.w};
      float bb[4] = {bv2.x,bv2.y,bv2.z,bv2.w};
      #pragma unroll
      for (int r = 0; r < 8; ++r)
        #pragma unroll
        for (int n = 0; n < 4; ++n)
          acc[r][n] = fmaf(aa[r], bb[n], acc[r][n]);
    }
    __syncthreads();
  }
  int o_base = o0 + ty * 8;
  #pragma unroll
  for (int r = 0; r < 8; ++r) {
    float bias = b0p[o_base + r];
    u16 h[4]; float s = 0.f, q = 0.f;
    #pragma unroll
    for (int n = 0; n < 4; ++n) {
      float v = acc[r][n] + bias;
      u16 hh = f2bf(v);
      float vr = bf2f(hh);              // stats on the rounded value GEMM2 will read
      h[n] = hh; s += vr; q += vr*vr;
    }
    *(ushort4*)(y0 + (b*CM_ + o_base + r) * N1_ + n0 + tx*4) = make_ushort4(h[0],h[1],h[2],h[3]);
    #pragma unroll
    for (int m = 1; m < 16; m <<= 1) { s += __shfl_xor(s, m); q += __shfl_xor(q, m); }
    if (tx == 0) {
      atomicAdd(&gsum[o_base + r], s);
      atomicAdd(&gsq[o_base + r], q);
    }
  }
}

// ---------------- K4: GEMM2 with fused BN0+ReLU on input, fp32 out + stats ----------------
__global__ __launch_bounds__(256) void gemm2_kernel(
    const u16* __restrict__ y0, const float* __restrict__ w1p, const float* __restrict__ b1p,
    const float* __restrict__ gsum0, const float* __restrict__ gsq0,
    const float* __restrict__ g0p, const float* __restrict__ be0p,
    float* __restrict__ out, float* __restrict__ gsum1, float* __restrict__ gsq1)
{
  __shared__ float As[16][128];
  __shared__ float Bs[16][64];
  __shared__ float a0s[CM_], bb0s[CM_];
  int t = threadIdx.x;
  {
    // inline finalize of BN0 stats (all 256 threads, one channel each)
    float m   = gsum0[t] * (1.f/65536.f);
    float var = gsq0[t] * (1.f/65536.f) - m*m;
    float rstd = rsqrtf(var + 1e-5f);
    float a = g0p[t] * rstd;
    a0s[t] = a; bb0s[t] = be0p[t] - m*a;
  }
  __syncthreads();
  int b  = blockIdx.y;
  int n0 = blockIdx.x * 64;
  int tx = t & 15, ty = t >> 4;
  int ar = t >> 1, ak = (t & 1) * 8;
  int bk = t >> 4, bn = (t & 15) * 4;
  float acc[8][4] = {};
  for (int k = 0; k < CM_; k += 16) {
    const float* wp = w1p + ar * CM_ + k + ak;
    float4 av0 = *(const float4*)wp;
    float4 av1 = *(const float4*)(wp + 4);
    As[ak+0][ar] = av0.x; As[ak+1][ar] = av0.y; As[ak+2][ar] = av0.z; As[ak+3][ar] = av0.w;
    As[ak+4][ar] = av1.x; As[ak+5][ar] = av1.y; As[ak+6][ar] = av1.z; As[ak+7][ar] = av1.w;
    int c = k + bk;
    const u16* ip = y0 + (b*CM_ + c) * N1_ + n0 + bn;
    uint2 u = *(const uint2*)ip;
    float a = a0s[c], bb = bb0s[c];
    float4 bv;
    bv.x = fmaxf(fmaf(__uint_as_float(u.x << 16),        a, bb), 0.f);
    bv.y = fmaxf(fmaf(__uint_as_float(u.x & 0xffff0000u),a, bb), 0.f);
    bv.z = fmaxf(fmaf(__uint_as_float(u.y << 16),        a, bb), 0.f);
    bv.w = fmaxf(fmaf(__uint_as_float(u.y & 0xffff0000u),a, bb), 0.f);
    *(float4*)&Bs[bk][bn] = bv;
    __syncthreads();
    #pragma unroll
    for (int kk = 0; kk < 16; ++kk) {
      float4 a0v = *(const float4*)&As[kk][ty*8];
      float4 a1v = *(const float4*)&As[kk][ty*8+4];
      float4 bv2 = *(const float4*)&Bs[kk][tx*4];
      float aa[8] = {a0v.x,a0v.y,a0v.z,a0v.w,a1v.x,a1v.y,a1v.z,a1v.w};
      float bbv[4] = {bv2.x,bv2.y,bv2.z,bv2.w};
      #pragma unroll
      for (int r = 0; r < 8; ++r)
        #pragma unroll
        for (int n = 0; n < 4; ++n)
          acc[r][n] = fmaf(aa[r], bbv[n], acc[r][n]);
    }
    __syncthreads();
  }
  int o_base = ty * 8;
  #pragma unroll
  for (int r = 0; r < 8; ++r) {
    float bias = b1p[o_base + r];
    float v0 = acc[r][0]+bias, v1 = acc[r][1]+bias, v2 = acc[r][2]+bias, v3 = acc[r][3]+bias;
    *(float4*)(out + (b*CO_ + o_base + r) * N1_ + n0 + tx*4) = make_float4(v0,v1,v2,v3);
    float s = v0+v1+v2+v3;
    float q = v0*v0+v1*v1+v2*v2+v3*v3;
    #pragma unroll
    for (int m = 1; m < 16; m <<= 1) { s += __shfl_xor(s, m); q += __shfl_xor(q, m); }
    if (tx == 0) {
      atomicAdd(&gsum1[o_base + r], s);
      atomicAdd(&gsq1[o_base + r], q);
    }
  }
}

// ---------------- K5: BN1 + ReLU in place on d_out ----------------
__global__ __launch_bounds__(256) void bnrelu_kernel(
    float* __restrict__ out, const float* __restrict__ gsum1, const float* __restrict__ gsq1,
    const float* __restrict__ g1p, const float* __restrict__ be1p)
{
  int idx = blockIdx.x * 256 + threadIdx.x;   // float4 index
  int c = (idx >> 10) & (CO_ - 1);            // 4096 floats per channel = 1024 float4s
  float m   = gsum1[c] * (1.f/65536.f);
  float var = gsq1[c] * (1.f/65536.f) - m*m;
  float rstd = rsqrtf(var + 1e-5f);
  float a = g1p[c] * rstd;
  float bb = be1p[c] - m*a;
  float4 v = ((const float4*)out)[idx];
  v.x = fmaxf(fmaf(v.x, a, bb), 0.f);
  v.y = fmaxf(fmaf(v.y, a, bb), 0.f);
  v.z = fmaxf(fmaf(v.z, a, bb), 0.f);
  v.w = fmaxf(fmaf(v.w, a, bb), 0.f);
  ((float4*)out)[idx] = v;
}

extern "C" void kernel_launch(void* const* d_in, const int* in_sizes, int n_in,
                              void* d_out, int out_size, void* d_ws, size_t ws_size,
                              hipStream_t stream)
{
  const float* xyz1  = (const float*)d_in[0];
  const float* xyz2  = (const float*)d_in[1];
  const float* feat1 = (const float*)d_in[2];
  const float* feat2 = (const float*)d_in[3];
  const float* w0    = (const float*)d_in[4];
  const float* b0    = (const float*)d_in[5];
  const float* g0    = (const float*)d_in[6];
  const float* be0   = (const float*)d_in[7];
  const float* w1    = (const float*)d_in[8];
  const float* b1    = (const float*)d_in[9];
  const float* g1    = (const float*)d_in[10];
  const float* be1   = (const float*)d_in[11];
  float* out = (float*)d_out;
  char* ws = (char*)d_ws;

  // workspace layout (bytes)
  u16*   interp  = (u16*)ws;                                   // 16*256*4096*2 = 33554432
  u16*   y0      = (u16*)(ws + 33554432);                      // 16*256*4096*2 = 33554432
  int*   idx_buf = (int*)(ws + 67108864);                      // 3*16*4096*4   = 786432
  float* w_buf   = (float*)(ws + 67108864 + 786432);           // 3*16*4096*4   = 786432
  float* stats   = (float*)(ws + 67108864 + 2*786432);
  float* gsum0 = stats;         // 256
  float* gsq0  = stats + 256;   // 256
  float* gsum1 = stats + 512;   // 128
  float* gsq1  = stats + 640;   // 128

  hipMemsetAsync(stats, 0, 768 * sizeof(float), stream);
  knn_kernel  <<<dim3(16,16),    256, 0, stream>>>(xyz1, xyz2, idx_buf, w_buf);
  interp_kernel<<<dim3(16,16,16),256, 0, stream>>>(feat2, idx_buf, w_buf, interp);
  gemm1_kernel<<<dim3(64,16,2),  256, 0, stream>>>(feat1, interp, w0, b0, y0, gsum0, gsq0);
  gemm2_kernel<<<dim3(64,16),    256, 0, stream>>>(y0, w1, b1, gsum0, gsq0, g0, be0, out, gsum1, gsq1);
  bnrelu_kernel<<<8192,          256, 0, stream>>>(out, gsum1, gsq1, g1, be1);
}

// Round 2
// 645.563 us; speedup vs baseline: 1.3768x; 1.3768x over previous
//
#include <hip/hip_runtime.h>
#include <hip/hip_bf16.h>

typedef unsigned short u16;
typedef __attribute__((ext_vector_type(8))) __bf16 bf16x8;
typedef __attribute__((ext_vector_type(4))) float floatx4;

#define B_   16
#define N1_  4096
#define N2_  1024
#define C1_  128
#define C2_  256
#define CIN_ 384
#define CM_  256
#define CO_  128

__device__ __forceinline__ u16 f2bf(float f) {
  unsigned u = __float_as_uint(f);
  u = (u + 0x7fffu + ((u >> 16) & 1u)) >> 16;
  return (u16)u;
}
__device__ __forceinline__ float bf2f(u16 h) {
  return __uint_as_float(((unsigned)h) << 16);
}

union U128 { uint4 u; bf16x8 v; u16 s[8]; };

__device__ __forceinline__ bf16x8 ldfrag(const u16* p) {
  U128 x; x.u = *(const uint4*)p; return x.v;
}
__device__ __forceinline__ uint4 pack8(const u16* h) {
  uint4 u;
  u.x = (unsigned)h[0] | ((unsigned)h[1] << 16);
  u.y = (unsigned)h[2] | ((unsigned)h[3] << 16);
  u.z = (unsigned)h[4] | ((unsigned)h[5] << 16);
  u.w = (unsigned)h[6] | ((unsigned)h[7] << 16);
  return u;
}

// ---------------- K0: cast weights to bf16 ----------------
__global__ __launch_bounds__(256) void castw_kernel(
    const float* __restrict__ w0, const float* __restrict__ w1,
    u16* __restrict__ w0b, u16* __restrict__ w1b)
{
  int i = blockIdx.x * 256 + threadIdx.x;     // 512 blocks -> 131072 threads
  if (i < CM_*CIN_) w0b[i] = f2bf(w0[i]);
  else              w1b[i - CM_*CIN_] = f2bf(w1[i - CM_*CIN_]);
}

// ---------------- K1: 3-NN (top-3 smallest sq dists) ----------------
__global__ __launch_bounds__(256) void knn_kernel(
    const float* __restrict__ xyz1, const float* __restrict__ xyz2,
    int* __restrict__ idx_out, float* __restrict__ w_out)
{
  __shared__ float sx[N2_], sy[N2_], sz[N2_];
  int b = blockIdx.y;
  const float* p2 = xyz2 + b * N2_ * 3;
  for (int t = threadIdx.x; t < N2_; t += 256) {
    sx[t] = p2[t*3+0]; sy[t] = p2[t*3+1]; sz[t] = p2[t*3+2];
  }
  __syncthreads();
  int i = blockIdx.x * 256 + threadIdx.x;
  const float* p1 = xyz1 + (b * N1_ + i) * 3;
  float x = p1[0], y = p1[1], z = p1[2];
  float d0 = 1e30f, d1 = 1e30f, d2 = 1e30f;
  int i0 = 0, i1 = 0, i2 = 0;
  for (int j = 0; j < N2_; ++j) {
    float dx = x - sx[j], dy = y - sy[j], dz = z - sz[j];
    float d = dx*dx + dy*dy + dz*dz;
    if (d < d2) {
      if (d < d0)      { d2=d1; i2=i1; d1=d0; i1=i0; d0=d; i0=j; }
      else if (d < d1) { d2=d1; i2=i1; d1=d;  i1=j; }
      else             { d2=d;  i2=j; }
    }
  }
  float w0 = 1.f/(d0+1e-8f), w1 = 1.f/(d1+1e-8f), w2 = 1.f/(d2+1e-8f);
  float inv = 1.f/(w0+w1+w2);
  int base = b*N1_ + i;
  idx_out[base]            = i0;
  idx_out[base +   B_*N1_] = i1;
  idx_out[base + 2*B_*N1_] = i2;
  w_out[base]              = w0*inv;
  w_out[base +   B_*N1_]   = w1*inv;
  w_out[base + 2*B_*N1_]   = w2*inv;
}

// ---------------- K2: build xcatT[b][n][c] bf16 (transpose feat1 + interp feat2) ----------------
__global__ __launch_bounds__(256) void prep_kernel(
    const float* __restrict__ feat1, const float* __restrict__ feat2,
    const int* __restrict__ idx_in, const float* __restrict__ w_in,
    u16* __restrict__ xcatT)
{
  __shared__ float sA[64][133];                 // pad 133: bank stride 5, conflict-free
  int b = blockIdx.y;
  int n0 = blockIdx.x * 64;
  int t = threadIdx.x;
  #pragma unroll
  for (int j = 0; j < 8; ++j) {
    int flat4 = t + j * 256;                    // 0..2047 float4s of the 128c x 64n tile
    int c = flat4 >> 4;
    int nn4 = (flat4 & 15) * 4;
    float4 v = *(const float4*)(feat1 + ((size_t)b*C1_ + c)*N1_ + n0 + nn4);
    sA[nn4+0][c] = v.x; sA[nn4+1][c] = v.y; sA[nn4+2][c] = v.z; sA[nn4+3][c] = v.w;
  }
  __syncthreads();
  int nn = t & 63, chunk = t >> 6;
  int n = n0 + nn;
  u16* xrow = xcatT + ((size_t)b*N1_ + n) * CIN_;
  // feat1 part: this thread writes channels [chunk*32, chunk*32+32)
  {
    int c0 = chunk * 32;
    #pragma unroll
    for (int g = 0; g < 4; ++g) {
      u16 h8[8];
      #pragma unroll
      for (int j = 0; j < 8; ++j) h8[j] = f2bf(sA[nn][c0 + g*8 + j]);
      *(uint4*)(xrow + c0 + g*8) = pack8(h8);
    }
  }
  // interp part: channels [128 + chunk*64, 128 + chunk*64 + 64)
  int base = b*N1_ + n;
  int i0 = idx_in[base], i1 = idx_in[base + B_*N1_], i2 = idx_in[base + 2*B_*N1_];
  float w0 = w_in[base], w1 = w_in[base + B_*N1_], w2 = w_in[base + 2*B_*N1_];
  const float* f2 = feat2 + ((size_t)b*C2_ + chunk*64) * N2_;
  #pragma unroll
  for (int g = 0; g < 8; ++g) {
    u16 h8[8];
    #pragma unroll
    for (int j = 0; j < 8; ++j) {
      const float* r = f2 + (g*8 + j) * N2_;
      h8[j] = f2bf(w0*r[i0] + w1*r[i1] + w2*r[i2]);
    }
    *(uint4*)(xrow + C1_ + chunk*64 + g*8) = pack8(h8);
  }
}

// ---------------- K3: GEMM1 MFMA  y0T[b][n][m] = w0b @ xcatT + b0, bf16 + stats ----------------
__global__ __launch_bounds__(256) void gemm1_mfma(
    const u16* __restrict__ xcatT, const u16* __restrict__ w0b,
    const float* __restrict__ b0p, u16* __restrict__ y0T,
    float* __restrict__ gsum, float* __restrict__ gsq)
{
  const int K = CIN_;
  int t = threadIdx.x;
  int wave = t >> 6, lane = t & 63;
  int col = lane & 15, quad = lane >> 4;
  int wm = wave >> 1, wn = wave & 1;
  int b = blockIdx.y;
  int m0 = blockIdx.z * 128 + wm * 64;
  int n0 = blockIdx.x * 128 + wn * 64;

  const u16* aptr = w0b + (size_t)(m0 + col) * K + quad * 8;
  const u16* bptr = xcatT + ((size_t)b * N1_ + n0 + col) * K + quad * 8;

  floatx4 acc[4][4] = {};
  bf16x8 af[4], bf[4], afn[4], bfn[4];
  #pragma unroll
  for (int i = 0; i < 4; ++i) { af[i] = ldfrag(aptr + i*16*K); bf[i] = ldfrag(bptr + i*16*K); }
  #pragma unroll 1
  for (int ks = 1; ks < K/32; ++ks) {
    int k = ks * 32;
    #pragma unroll
    for (int i = 0; i < 4; ++i) afn[i] = ldfrag(aptr + i*16*K + k);
    #pragma unroll
    for (int i = 0; i < 4; ++i) bfn[i] = ldfrag(bptr + i*16*K + k);
    #pragma unroll
    for (int mt = 0; mt < 4; ++mt)
      #pragma unroll
      for (int nt = 0; nt < 4; ++nt)
        acc[mt][nt] = __builtin_amdgcn_mfma_f32_16x16x32_bf16(af[mt], bf[nt], acc[mt][nt], 0, 0, 0);
    #pragma unroll
    for (int i = 0; i < 4; ++i) { af[i] = afn[i]; bf[i] = bfn[i]; }
  }
  #pragma unroll
  for (int mt = 0; mt < 4; ++mt)
    #pragma unroll
    for (int nt = 0; nt < 4; ++nt)
      acc[mt][nt] = __builtin_amdgcn_mfma_f32_16x16x32_bf16(af[mt], bf[nt], acc[mt][nt], 0, 0, 0);

  // epilogue: bias, bf16 round, store y0T[b][n][m], stats on rounded values
  #pragma unroll
  for (int mt = 0; mt < 4; ++mt) {
    float4 bias4 = *(const float4*)(b0p + m0 + mt*16 + quad*4);
    float bia[4] = {bias4.x, bias4.y, bias4.z, bias4.w};
    float s[4] = {}, q[4] = {};
    #pragma unroll
    for (int nt = 0; nt < 4; ++nt) {
      int n = n0 + nt*16 + col;
      u16 h[4];
      #pragma unroll
      for (int r = 0; r < 4; ++r) {
        float v = acc[mt][nt][r] + bia[r];
        u16 hh = f2bf(v);
        float vr = bf2f(hh);
        h[r] = hh; s[r] += vr; q[r] += vr*vr;
      }
      *(ushort4*)(y0T + ((size_t)b*N1_ + n)*CM_ + m0 + mt*16 + quad*4) = make_ushort4(h[0],h[1],h[2],h[3]);
    }
    #pragma unroll
    for (int r = 0; r < 4; ++r) {
      float ss = s[r], qq = q[r];
      #pragma unroll
      for (int msk = 1; msk < 16; msk <<= 1) { ss += __shfl_xor(ss, msk); qq += __shfl_xor(qq, msk); }
      if (col == 0) {
        atomicAdd(&gsum[m0 + mt*16 + quad*4 + r], ss);
        atomicAdd(&gsq [m0 + mt*16 + quad*4 + r], qq);
      }
    }
  }
}

// ---------------- K3.5: BN0 + ReLU in place on y0T (bf16) ----------------
__global__ __launch_bounds__(256) void bn0relu_kernel(
    u16* __restrict__ y0T,
    const float* __restrict__ gsum0, const float* __restrict__ gsq0,
    const float* __restrict__ g0p, const float* __restrict__ be0p)
{
  __shared__ float a0s[CM_], bb0s[CM_];
  int t = threadIdx.x;
  {
    float m   = gsum0[t] * (1.f/65536.f);
    float var = gsq0[t] * (1.f/65536.f) - m*m;
    float rstd = rsqrtf(var + 1e-5f);
    float a = g0p[t] * rstd;
    a0s[t] = a; bb0s[t] = be0p[t] - m*a;
  }
  __syncthreads();
  size_t idx = (size_t)blockIdx.x * 256 + t;       // uint4 index; 8192 blocks cover 2^21
  int c0 = ((int)idx & 31) * 8;                    // CM_=256 bf16 per point = 32 uint4
  U128 x; x.u = ((uint4*)y0T)[idx];
  u16 h8[8];
  #pragma unroll
  for (int j = 0; j < 8; ++j) {
    float v = fmaxf(fmaf(bf2f(x.s[j]), a0s[c0+j], bb0s[c0+j]), 0.f);
    h8[j] = f2bf(v);
  }
  ((uint4*)y0T)[idx] = pack8(h8);
}

// ---------------- K4: GEMM2 MFMA  out[b][m][n] = w1b @ h0 + b1, fp32 + stats ----------------
__global__ __launch_bounds__(256) void gemm2_mfma(
    const u16* __restrict__ h0, const u16* __restrict__ w1b,
    const float* __restrict__ b1p, float* __restrict__ out,
    float* __restrict__ gsum, float* __restrict__ gsq)
{
  const int K = CM_;
  int t = threadIdx.x;
  int wave = t >> 6, lane = t & 63;
  int col = lane & 15, quad = lane >> 4;
  int wm = wave >> 1, wn = wave & 1;
  int b = blockIdx.y;
  int m0 = wm * 64;                                // M=128 total
  int n0 = blockIdx.x * 128 + wn * 64;

  const u16* aptr = w1b + (size_t)(m0 + col) * K + quad * 8;
  const u16* bptr = h0 + ((size_t)b * N1_ + n0 + col) * K + quad * 8;

  floatx4 acc[4][4] = {};
  bf16x8 af[4], bf[4], afn[4], bfn[4];
  #pragma unroll
  for (int i = 0; i < 4; ++i) { af[i] = ldfrag(aptr + i*16*K); bf[i] = ldfrag(bptr + i*16*K); }
  #pragma unroll 1
  for (int ks = 1; ks < K/32; ++ks) {
    int k = ks * 32;
    #pragma unroll
    for (int i = 0; i < 4; ++i) afn[i] = ldfrag(aptr + i*16*K + k);
    #pragma unroll
    for (int i = 0; i < 4; ++i) bfn[i] = ldfrag(bptr + i*16*K + k);
    #pragma unroll
    for (int mt = 0; mt < 4; ++mt)
      #pragma unroll
      for (int nt = 0; nt < 4; ++nt)
        acc[mt][nt] = __builtin_amdgcn_mfma_f32_16x16x32_bf16(af[mt], bf[nt], acc[mt][nt], 0, 0, 0);
    #pragma unroll
    for (int i = 0; i < 4; ++i) { af[i] = afn[i]; bf[i] = bfn[i]; }
  }
  #pragma unroll
  for (int mt = 0; mt < 4; ++mt)
    #pragma unroll
    for (int nt = 0; nt < 4; ++nt)
      acc[mt][nt] = __builtin_amdgcn_mfma_f32_16x16x32_bf16(af[mt], bf[nt], acc[mt][nt], 0, 0, 0);

  #pragma unroll
  for (int mt = 0; mt < 4; ++mt) {
    float4 bias4 = *(const float4*)(b1p + m0 + mt*16 + quad*4);
    float bia[4] = {bias4.x, bias4.y, bias4.z, bias4.w};
    float s[4] = {}, q[4] = {};
    #pragma unroll
    for (int nt = 0; nt < 4; ++nt) {
      int n = n0 + nt*16 + col;
      #pragma unroll
      for (int r = 0; r < 4; ++r) {
        float v = acc[mt][nt][r] + bia[r];
        out[((size_t)b*CO_ + m0 + mt*16 + quad*4 + r)*N1_ + n] = v;
        s[r] += v; q[r] += v*v;
      }
    }
    #pragma unroll
    for (int r = 0; r < 4; ++r) {
      float ss = s[r], qq = q[r];
      #pragma unroll
      for (int msk = 1; msk < 16; msk <<= 1) { ss += __shfl_xor(ss, msk); qq += __shfl_xor(qq, msk); }
      if (col == 0) {
        atomicAdd(&gsum[m0 + mt*16 + quad*4 + r], ss);
        atomicAdd(&gsq [m0 + mt*16 + quad*4 + r], qq);
      }
    }
  }
}

// ---------------- K5: BN1 + ReLU in place on d_out ----------------
__global__ __launch_bounds__(256) void bnrelu_kernel(
    float* __restrict__ out, const float* __restrict__ gsum1, const float* __restrict__ gsq1,
    const float* __restrict__ g1p, const float* __restrict__ be1p)
{
  int idx = blockIdx.x * 256 + threadIdx.x;   // float4 index
  int c = (idx >> 10) & (CO_ - 1);
  float m   = gsum1[c] * (1.f/65536.f);
  float var = gsq1[c] * (1.f/65536.f) - m*m;
  float rstd = rsqrtf(var + 1e-5f);
  float a = g1p[c] * rstd;
  float bb = be1p[c] - m*a;
  float4 v = ((const float4*)out)[idx];
  v.x = fmaxf(fmaf(v.x, a, bb), 0.f);
  v.y = fmaxf(fmaf(v.y, a, bb), 0.f);
  v.z = fmaxf(fmaf(v.z, a, bb), 0.f);
  v.w = fmaxf(fmaf(v.w, a, bb), 0.f);
  ((float4*)out)[idx] = v;
}

extern "C" void kernel_launch(void* const* d_in, const int* in_sizes, int n_in,
                              void* d_out, int out_size, void* d_ws, size_t ws_size,
                              hipStream_t stream)
{
  const float* xyz1  = (const float*)d_in[0];
  const float* xyz2  = (const float*)d_in[1];
  const float* feat1 = (const float*)d_in[2];
  const float* feat2 = (const float*)d_in[3];
  const float* w0    = (const float*)d_in[4];
  const float* b0    = (const float*)d_in[5];
  const float* g0    = (const float*)d_in[6];
  const float* be0   = (const float*)d_in[7];
  const float* w1    = (const float*)d_in[8];
  const float* b1    = (const float*)d_in[9];
  const float* g1    = (const float*)d_in[10];
  const float* be1   = (const float*)d_in[11];
  float* out = (float*)d_out;
  char* ws = (char*)d_ws;

  // workspace layout (bytes)
  u16*   xcatT   = (u16*)ws;                                   // 16*4096*384*2 = 50331648
  u16*   y0T     = (u16*)(ws + 50331648);                      // 16*4096*256*2 = 33554432
  u16*   w0b     = (u16*)(ws + 83886080);                      // 98304*2       = 196608
  u16*   w1b     = (u16*)(ws + 84082688);                      // 32768*2       = 65536
  int*   idx_buf = (int*)(ws + 84148224);                      // 3*16*4096*4   = 786432
  float* w_buf   = (float*)(ws + 84934656);                    // 3*16*4096*4   = 786432
  float* stats   = (float*)(ws + 85721088);                    // 768*4
  float* gsum0 = stats;         // 256
  float* gsq0  = stats + 256;   // 256
  float* gsum1 = stats + 512;   // 128
  float* gsq1  = stats + 640;   // 128

  hipMemsetAsync(stats, 0, 768 * sizeof(float), stream);
  castw_kernel  <<<512,           256, 0, stream>>>(w0, w1, w0b, w1b);
  knn_kernel    <<<dim3(16,16),   256, 0, stream>>>(xyz1, xyz2, idx_buf, w_buf);
  prep_kernel   <<<dim3(64,16),   256, 0, stream>>>(feat1, feat2, idx_buf, w_buf, xcatT);
  gemm1_mfma    <<<dim3(32,16,2), 256, 0, stream>>>(xcatT, w0b, b0, y0T, gsum0, gsq0);
  bn0relu_kernel<<<8192,          256, 0, stream>>>(y0T, gsum0, gsq0, g0, be0);
  gemm2_mfma    <<<dim3(32,16),   256, 0, stream>>>(y0T, w1b, b1, out, gsum1, gsq1);
  bnrelu_kernel <<<8192,          256, 0, stream>>>(out, gsum1, gsq1, g1, be1);
}

// Round 3
// 588.476 us; speedup vs baseline: 1.5103x; 1.0970x over previous
//
#include <hip/hip_runtime.h>
#include <hip/hip_bf16.h>

typedef unsigned short u16;
typedef __attribute__((ext_vector_type(8))) __bf16 bf16x8;
typedef __attribute__((ext_vector_type(4))) float floatx4;

#define B_   16
#define N1_  4096
#define N2_  1024
#define C1_  128
#define C2_  256
#define CIN_ 384
#define CM_  256
#define CO_  128

__device__ __forceinline__ u16 f2bf(float f) {
  unsigned u = __float_as_uint(f);
  u = (u + 0x7fffu + ((u >> 16) & 1u)) >> 16;
  return (u16)u;
}
__device__ __forceinline__ float bf2f(u16 h) {
  return __uint_as_float(((unsigned)h) << 16);
}

union U128 { uint4 u; bf16x8 v; u16 s[8]; };

__device__ __forceinline__ bf16x8 ldfrag(const u16* p) {
  U128 x; x.u = *(const uint4*)p; return x.v;
}
__device__ __forceinline__ uint4 pack8(const u16* h) {
  uint4 u;
  u.x = (unsigned)h[0] | ((unsigned)h[1] << 16);
  u.y = (unsigned)h[2] | ((unsigned)h[3] << 16);
  u.z = (unsigned)h[4] | ((unsigned)h[5] << 16);
  u.w = (unsigned)h[6] | ((unsigned)h[7] << 16);
  return u;
}

// Tiled operand layout (MFMA-fragment-major):
//   frag(tile_m_or_n, kt) at [tile][kt][lane][8] u16, lane = quad*16+col,
//   element j = M[row=col][k = kt*32 + quad*8 + j].
//   A wave's 16B/lane fragment load is then base + lane*16B: fully coalesced.

// ---------------- K0: cast weights to bf16, tiled ----------------
__global__ __launch_bounds__(256) void castw_kernel(
    const float* __restrict__ w0, const float* __restrict__ w1,
    u16* __restrict__ w0b, u16* __restrict__ w1b)
{
  int i = blockIdx.x * 256 + threadIdx.x;          // 64 blocks = 16384 threads
  if (i < 12288) {                                  // w0: 256 rows x 48 chunks
    int m = i / 48, kc = i % 48;
    const float* p = w0 + m * CIN_ + kc * 8;
    u16 h8[8];
    #pragma unroll
    for (int j = 0; j < 8; ++j) h8[j] = f2bf(p[j]);
    int mt = m >> 4, col = m & 15, kt = kc >> 2, quad = kc & 3;
    *(uint4*)(w0b + ((mt*12 + kt)*512 + (quad*16 + col)*8)) = pack8(h8);
  } else {                                          // w1: 128 rows x 32 chunks
    int i2 = i - 12288;
    int m = i2 >> 5, kc = i2 & 31;
    const float* p = w1 + m * CM_ + kc * 8;
    u16 h8[8];
    #pragma unroll
    for (int j = 0; j < 8; ++j) h8[j] = f2bf(p[j]);
    int mt = m >> 4, col = m & 15, kt = kc >> 2, quad = kc & 3;
    *(uint4*)(w1b + ((mt*8 + kt)*512 + (quad*16 + col)*8)) = pack8(h8);
  }
}

// ---------------- K1: 3-NN ----------------
__global__ __launch_bounds__(256) void knn_kernel(
    const float* __restrict__ xyz1, const float* __restrict__ xyz2,
    int* __restrict__ idx_out, float* __restrict__ w_out)
{
  __shared__ float sx[N2_], sy[N2_], sz[N2_];
  int b = blockIdx.y;
  const float* p2 = xyz2 + b * N2_ * 3;
  for (int t = threadIdx.x; t < N2_; t += 256) {
    sx[t] = p2[t*3+0]; sy[t] = p2[t*3+1]; sz[t] = p2[t*3+2];
  }
  __syncthreads();
  int i = blockIdx.x * 256 + threadIdx.x;
  const float* p1 = xyz1 + (b * N1_ + i) * 3;
  float x = p1[0], y = p1[1], z = p1[2];
  float d0 = 1e30f, d1 = 1e30f, d2 = 1e30f;
  int i0 = 0, i1 = 0, i2 = 0;
  for (int j = 0; j < N2_; ++j) {
    float dx = x - sx[j], dy = y - sy[j], dz = z - sz[j];
    float d = dx*dx + dy*dy + dz*dz;
    if (d < d2) {
      if (d < d0)      { d2=d1; i2=i1; d1=d0; i1=i0; d0=d; i0=j; }
      else if (d < d1) { d2=d1; i2=i1; d1=d;  i1=j; }
      else             { d2=d;  i2=j; }
    }
  }
  float w0 = 1.f/(d0+1e-8f), w1 = 1.f/(d1+1e-8f), w2 = 1.f/(d2+1e-8f);
  float inv = 1.f/(w0+w1+w2);
  int base = b*N1_ + i;
  idx_out[base]            = i0;
  idx_out[base +   B_*N1_] = i1;
  idx_out[base + 2*B_*N1_] = i2;
  w_out[base]              = w0*inv;
  w_out[base +   B_*N1_]   = w1*inv;
  w_out[base + 2*B_*N1_]   = w2*inv;
}

// ---------------- K1.5: transpose feat2 -> feat2T[b][n2][c] fp32 ----------------
__global__ __launch_bounds__(256) void tr2_kernel(
    const float* __restrict__ feat2, float* __restrict__ feat2T)
{
  __shared__ float sA[64][257];                    // 257: conflict-free column reads
  int b = blockIdx.y;
  int n0 = blockIdx.x * 64;
  int t = threadIdx.x;
  #pragma unroll
  for (int j = 0; j < 16; ++j) {
    int flat4 = t + j * 256;                       // 4096 float4s: 256c x 64n
    int c = flat4 >> 4, nn4 = (flat4 & 15) * 4;
    float4 v = *(const float4*)(feat2 + ((size_t)b*C2_ + c)*N2_ + n0 + nn4);
    sA[nn4+0][c] = v.x; sA[nn4+1][c] = v.y; sA[nn4+2][c] = v.z; sA[nn4+3][c] = v.w;
  }
  __syncthreads();
  int nn = t & 63, chunk = t >> 6;                 // 64 channels per thread
  float* dst = feat2T + ((size_t)b*N2_ + n0 + nn)*C2_ + chunk*64;
  #pragma unroll
  for (int g = 0; g < 16; ++g) {
    int c = chunk*64 + g*4;
    float4 v = make_float4(sA[nn][c], sA[nn][c+1], sA[nn][c+2], sA[nn][c+3]);
    *(float4*)(dst + g*4) = v;
  }
}

// ---------------- K2: build xcat tiled (feat1 transpose + 3NN interp) ----------------
__global__ __launch_bounds__(256) void prep_kernel(
    const float* __restrict__ feat1, const float* __restrict__ feat2T,
    const int* __restrict__ idx_in, const float* __restrict__ w_in,
    u16* __restrict__ xcatT)
{
  __shared__ float sA[64][133];
  int b = blockIdx.y;
  int n0 = blockIdx.x * 64;
  int t = threadIdx.x;
  #pragma unroll
  for (int j = 0; j < 8; ++j) {
    int flat4 = t + j * 256;                       // 2048 float4s: 128c x 64n
    int c = flat4 >> 4, nn4 = (flat4 & 15) * 4;
    float4 v = *(const float4*)(feat1 + ((size_t)b*C1_ + c)*N1_ + n0 + nn4);
    sA[nn4+0][c] = v.x; sA[nn4+1][c] = v.y; sA[nn4+2][c] = v.z; sA[nn4+3][c] = v.w;
  }
  __syncthreads();
  int nn = t & 63, chunk = t >> 6;
  int n = n0 + nn, nt = n >> 4, col = n & 15;
  u16* tb = xcatT + ((size_t)b*256 + nt)*12*512;
  // feat1 part: channels [chunk*32, chunk*32+32) -> kt=chunk, quad=g
  #pragma unroll
  for (int g = 0; g < 4; ++g) {
    int c0 = chunk*32 + g*8;
    u16 h8[8];
    #pragma unroll
    for (int j = 0; j < 8; ++j) h8[j] = f2bf(sA[nn][c0 + j]);
    *(uint4*)(tb + (size_t)chunk*512 + (g*16 + col)*8) = pack8(h8);
  }
  // interp part: channels [128 + chunk*64, 128 + chunk*64 + 64)
  int base = b*N1_ + n;
  int i0 = idx_in[base], i1 = idx_in[base + B_*N1_], i2 = idx_in[base + 2*B_*N1_];
  float w0 = w_in[base], w1 = w_in[base + B_*N1_], w2 = w_in[base + 2*B_*N1_];
  const float* r0 = feat2T + ((size_t)b*N2_ + i0)*C2_ + chunk*64;
  const float* r1 = feat2T + ((size_t)b*N2_ + i1)*C2_ + chunk*64;
  const float* r2 = feat2T + ((size_t)b*N2_ + i2)*C2_ + chunk*64;
  #pragma unroll
  for (int h = 0; h < 8; ++h) {
    float4 a0 = *(const float4*)(r0 + h*8),     a1 = *(const float4*)(r0 + h*8 + 4);
    float4 b0 = *(const float4*)(r1 + h*8),     b1 = *(const float4*)(r1 + h*8 + 4);
    float4 c0 = *(const float4*)(r2 + h*8),     c1 = *(const float4*)(r2 + h*8 + 4);
    u16 h8[8];
    h8[0] = f2bf(w0*a0.x + w1*b0.x + w2*c0.x);
    h8[1] = f2bf(w0*a0.y + w1*b0.y + w2*c0.y);
    h8[2] = f2bf(w0*a0.z + w1*b0.z + w2*c0.z);
    h8[3] = f2bf(w0*a0.w + w1*b0.w + w2*c0.w);
    h8[4] = f2bf(w0*a1.x + w1*b1.x + w2*c1.x);
    h8[5] = f2bf(w0*a1.y + w1*b1.y + w2*c1.y);
    h8[6] = f2bf(w0*a1.z + w1*b1.z + w2*c1.z);
    h8[7] = f2bf(w0*a1.w + w1*b1.w + w2*c1.w);
    int c = C1_ + chunk*64 + h*8;
    int kt = c >> 5, quad = (c >> 3) & 3;
    *(uint4*)(tb + (size_t)kt*512 + (quad*16 + col)*8) = pack8(h8);
  }
}

// ---------------- K3: GEMM1 MFMA (tiled operands, coalesced frag loads) ----------------
__global__ __launch_bounds__(256) void gemm1_mfma(
    const u16* __restrict__ xcatT, const u16* __restrict__ w0b,
    const float* __restrict__ b0p, u16* __restrict__ y0T,
    float* __restrict__ gsum, float* __restrict__ gsq)
{
  int t = threadIdx.x;
  int wave = t >> 6, lane = t & 63;
  int col = lane & 15, quad = lane >> 4;
  int wm = wave >> 1, wn = wave & 1;
  int b = blockIdx.y;
  int mtb = blockIdx.z*8 + wm*4;                   // 16-row m-tiles
  int ntb = blockIdx.x*8 + wn*4;                   // 16-col n-tiles

  const u16* ap = w0b + lane*8;
  const u16* bp = xcatT + ((size_t)(b*256 + ntb)*12)*512 + lane*8;

  floatx4 acc[4][4] = {};
  bf16x8 af[4], bf[4], afn[4], bfn[4];
  #pragma unroll
  for (int i = 0; i < 4; ++i) {
    af[i] = ldfrag(ap + (size_t)((mtb+i)*12)*512);
    bf[i] = ldfrag(bp + (size_t)(i*12)*512);
  }
  #pragma unroll 1
  for (int kt = 1; kt < 12; ++kt) {
    #pragma unroll
    for (int i = 0; i < 4; ++i) afn[i] = ldfrag(ap + (size_t)((mtb+i)*12 + kt)*512);
    #pragma unroll
    for (int i = 0; i < 4; ++i) bfn[i] = ldfrag(bp + (size_t)(i*12 + kt)*512);
    #pragma unroll
    for (int mt = 0; mt < 4; ++mt)
      #pragma unroll
      for (int nt = 0; nt < 4; ++nt)
        acc[mt][nt] = __builtin_amdgcn_mfma_f32_16x16x32_bf16(af[mt], bf[nt], acc[mt][nt], 0, 0, 0);
    #pragma unroll
    for (int i = 0; i < 4; ++i) { af[i] = afn[i]; bf[i] = bfn[i]; }
  }
  #pragma unroll
  for (int mt = 0; mt < 4; ++mt)
    #pragma unroll
    for (int nt = 0; nt < 4; ++nt)
      acc[mt][nt] = __builtin_amdgcn_mfma_f32_16x16x32_bf16(af[mt], bf[nt], acc[mt][nt], 0, 0, 0);

  // epilogue: bias, bf16 round, store into gemm2's B-tiled layout, stats
  int m0 = blockIdx.z*128 + wm*64;
  #pragma unroll
  for (int mt = 0; mt < 4; ++mt) {
    float4 bias4 = *(const float4*)(b0p + m0 + mt*16 + quad*4);
    float bia[4] = {bias4.x, bias4.y, bias4.z, bias4.w};
    int kt_out = (m0 >> 5) + (mt >> 1);
    int quad_out = ((mt & 1) << 1) | (quad >> 1);
    int j0 = (quad & 1) * 4;
    float s[4] = {}, q[4] = {};
    #pragma unroll
    for (int nt = 0; nt < 4; ++nt) {
      int nt_g = ntb + nt;
      u16 h[4];
      #pragma unroll
      for (int r = 0; r < 4; ++r) {
        float v = acc[mt][nt][r] + bia[r];
        u16 hh = f2bf(v);
        float vr = bf2f(hh);
        h[r] = hh; s[r] += vr; q[r] += vr*vr;
      }
      *(ushort4*)(y0T + (((size_t)b*256 + nt_g)*8 + kt_out)*512 + (quad_out*16 + col)*8 + j0)
          = make_ushort4(h[0], h[1], h[2], h[3]);
    }
    #pragma unroll
    for (int r = 0; r < 4; ++r) {
      float ss = s[r], qq = q[r];
      #pragma unroll
      for (int msk = 1; msk < 16; msk <<= 1) { ss += __shfl_xor(ss, msk); qq += __shfl_xor(qq, msk); }
      if (col == 0) {
        atomicAdd(&gsum[m0 + mt*16 + quad*4 + r], ss);
        atomicAdd(&gsq [m0 + mt*16 + quad*4 + r], qq);
      }
    }
  }
}

// ---------------- K4: GEMM2 MFMA, BN0+ReLU fused on B-load ----------------
__global__ __launch_bounds__(256) void gemm2_mfma(
    const u16* __restrict__ y0T, const u16* __restrict__ w1b,
    const float* __restrict__ b1p,
    const float* __restrict__ gsum0, const float* __restrict__ gsq0,
    const float* __restrict__ g0p, const float* __restrict__ be0p,
    float* __restrict__ out, float* __restrict__ gsum, float* __restrict__ gsq)
{
  __shared__ float a0s[CM_], bb0s[CM_];
  int t = threadIdx.x;
  {
    float m   = gsum0[t] * (1.f/65536.f);
    float var = gsq0[t] * (1.f/65536.f) - m*m;
    float rstd = rsqrtf(var + 1e-5f);
    float a = g0p[t] * rstd;
    a0s[t] = a; bb0s[t] = be0p[t] - m*a;
  }
  __syncthreads();
  int wave = t >> 6, lane = t & 63;
  int col = lane & 15, quad = lane >> 4;
  int wm = wave >> 1, wn = wave & 1;
  int b = blockIdx.y;
  int mtb = wm*4;
  int ntb = blockIdx.x*8 + wn*4;

  const u16* ap = w1b + lane*8;
  const u16* bp = y0T + ((size_t)(b*256 + ntb)*8)*512 + lane*8;

  floatx4 acc[4][4] = {};
  bf16x8 af[4], afn[4];
  U128 braw[4], brawn[4];
  #pragma unroll
  for (int i = 0; i < 4; ++i) {
    af[i] = ldfrag(ap + (size_t)((mtb+i)*8)*512);
    braw[i].u = *(const uint4*)(bp + (size_t)(i*8)*512);
  }
  #pragma unroll 1
  for (int kt = 1; kt < 8; ++kt) {
    #pragma unroll
    for (int i = 0; i < 4; ++i) afn[i] = ldfrag(ap + (size_t)((mtb+i)*8 + kt)*512);
    #pragma unroll
    for (int i = 0; i < 4; ++i) brawn[i].u = *(const uint4*)(bp + (size_t)(i*8 + kt)*512);
    int c0 = (kt-1)*32 + quad*8;
    float4 av0 = *(const float4*)&a0s[c0], av1 = *(const float4*)&a0s[c0+4];
    float4 bv0 = *(const float4*)&bb0s[c0], bv1 = *(const float4*)&bb0s[c0+4];
    float av[8] = {av0.x,av0.y,av0.z,av0.w,av1.x,av1.y,av1.z,av1.w};
    float bv[8] = {bv0.x,bv0.y,bv0.z,bv0.w,bv1.x,bv1.y,bv1.z,bv1.w};
    bf16x8 bfv[4];
    #pragma unroll
    for (int i = 0; i < 4; ++i) {
      u16 h8[8];
      #pragma unroll
      for (int j = 0; j < 8; ++j)
        h8[j] = f2bf(fmaxf(fmaf(bf2f(braw[i].s[j]), av[j], bv[j]), 0.f));
      U128 x; x.u = pack8(h8); bfv[i] = x.v;
    }
    #pragma unroll
    for (int mt = 0; mt < 4; ++mt)
      #pragma unroll
      for (int nt = 0; nt < 4; ++nt)
        acc[mt][nt] = __builtin_amdgcn_mfma_f32_16x16x32_bf16(af[mt], bfv[nt], acc[mt][nt], 0, 0, 0);
    #pragma unroll
    for (int i = 0; i < 4; ++i) { af[i] = afn[i]; braw[i] = brawn[i]; }
  }
  {
    int c0 = 7*32 + quad*8;
    float4 av0 = *(const float4*)&a0s[c0], av1 = *(const float4*)&a0s[c0+4];
    float4 bv0 = *(const float4*)&bb0s[c0], bv1 = *(const float4*)&bb0s[c0+4];
    float av[8] = {av0.x,av0.y,av0.z,av0.w,av1.x,av1.y,av1.z,av1.w};
    float bv[8] = {bv0.x,bv0.y,bv0.z,bv0.w,bv1.x,bv1.y,bv1.z,bv1.w};
    bf16x8 bfv[4];
    #pragma unroll
    for (int i = 0; i < 4; ++i) {
      u16 h8[8];
      #pragma unroll
      for (int j = 0; j < 8; ++j)
        h8[j] = f2bf(fmaxf(fmaf(bf2f(braw[i].s[j]), av[j], bv[j]), 0.f));
      U128 x; x.u = pack8(h8); bfv[i] = x.v;
    }
    #pragma unroll
    for (int mt = 0; mt < 4; ++mt)
      #pragma unroll
      for (int nt = 0; nt < 4; ++nt)
        acc[mt][nt] = __builtin_amdgcn_mfma_f32_16x16x32_bf16(af[mt], bfv[nt], acc[mt][nt], 0, 0, 0);
  }

  int m0 = wm*64;
  int n0 = blockIdx.x*128 + wn*64;
  #pragma unroll
  for (int mt = 0; mt < 4; ++mt) {
    float4 bias4 = *(const float4*)(b1p + m0 + mt*16 + quad*4);
    float bia[4] = {bias4.x, bias4.y, bias4.z, bias4.w};
    float s[4] = {}, q[4] = {};
    #pragma unroll
    for (int nt = 0; nt < 4; ++nt) {
      int n = n0 + nt*16 + col;
      #pragma unroll
      for (int r = 0; r < 4; ++r) {
        float v = acc[mt][nt][r] + bia[r];
        out[((size_t)b*CO_ + m0 + mt*16 + quad*4 + r)*N1_ + n] = v;
        s[r] += v; q[r] += v*v;
      }
    }
    #pragma unroll
    for (int r = 0; r < 4; ++r) {
      float ss = s[r], qq = q[r];
      #pragma unroll
      for (int msk = 1; msk < 16; msk <<= 1) { ss += __shfl_xor(ss, msk); qq += __shfl_xor(qq, msk); }
      if (col == 0) {
        atomicAdd(&gsum[m0 + mt*16 + quad*4 + r], ss);
        atomicAdd(&gsq [m0 + mt*16 + quad*4 + r], qq);
      }
    }
  }
}

// ---------------- K5: BN1 + ReLU in place on d_out ----------------
__global__ __launch_bounds__(256) void bnrelu_kernel(
    float* __restrict__ out, const float* __restrict__ gsum1, const float* __restrict__ gsq1,
    const float* __restrict__ g1p, const float* __restrict__ be1p)
{
  int idx = blockIdx.x * 256 + threadIdx.x;   // float4 index
  int c = (idx >> 10) & (CO_ - 1);
  float m   = gsum1[c] * (1.f/65536.f);
  float var = gsq1[c] * (1.f/65536.f) - m*m;
  float rstd = rsqrtf(var + 1e-5f);
  float a = g1p[c] * rstd;
  float bb = be1p[c] - m*a;
  float4 v = ((const float4*)out)[idx];
  v.x = fmaxf(fmaf(v.x, a, bb), 0.f);
  v.y = fmaxf(fmaf(v.y, a, bb), 0.f);
  v.z = fmaxf(fmaf(v.z, a, bb), 0.f);
  v.w = fmaxf(fmaf(v.w, a, bb), 0.f);
  ((float4*)out)[idx] = v;
}

extern "C" void kernel_launch(void* const* d_in, const int* in_sizes, int n_in,
                              void* d_out, int out_size, void* d_ws, size_t ws_size,
                              hipStream_t stream)
{
  const float* xyz1  = (const float*)d_in[0];
  const float* xyz2  = (const float*)d_in[1];
  const float* feat1 = (const float*)d_in[2];
  const float* feat2 = (const float*)d_in[3];
  const float* w0    = (const float*)d_in[4];
  const float* b0    = (const float*)d_in[5];
  const float* g0    = (const float*)d_in[6];
  const float* be0   = (const float*)d_in[7];
  const float* w1    = (const float*)d_in[8];
  const float* b1    = (const float*)d_in[9];
  const float* g1    = (const float*)d_in[10];
  const float* be1   = (const float*)d_in[11];
  float* out = (float*)d_out;
  char* ws = (char*)d_ws;

  // workspace layout (bytes) — feat2T aliases y0T (disjoint lifetimes)
  u16*   xcatT   = (u16*)ws;                                   // 50331648
  u16*   y0T     = (u16*)(ws + 50331648);                      // 33554432
  float* feat2T  = (float*)(ws + 50331648);                    // 16777216 (alias, used pre-gemm1)
  u16*   w0b     = (u16*)(ws + 83886080);                      // 196608
  u16*   w1b     = (u16*)(ws + 84082688);                      // 65536
  int*   idx_buf = (int*)(ws + 84148224);                      // 786432
  float* w_buf   = (float*)(ws + 84934656);                    // 786432
  float* stats   = (float*)(ws + 85721088);                    // 768*4
  float* gsum0 = stats;
  float* gsq0  = stats + 256;
  float* gsum1 = stats + 512;
  float* gsq1  = stats + 640;

  hipMemsetAsync(stats, 0, 768 * sizeof(float), stream);
  castw_kernel<<<64,            256, 0, stream>>>(w0, w1, w0b, w1b);
  knn_kernel  <<<dim3(16,16),   256, 0, stream>>>(xyz1, xyz2, idx_buf, w_buf);
  tr2_kernel  <<<dim3(16,16),   256, 0, stream>>>(feat2, feat2T);
  prep_kernel <<<dim3(64,16),   256, 0, stream>>>(feat1, feat2T, idx_buf, w_buf, xcatT);
  gemm1_mfma  <<<dim3(32,16,2), 256, 0, stream>>>(xcatT, w0b, b0, y0T, gsum0, gsq0);
  gemm2_mfma  <<<dim3(32,16),   256, 0, stream>>>(y0T, w1b, b1, gsum0, gsq0, g0, be0, out, gsum1, gsq1);
  bnrelu_kernel<<<8192,         256, 0, stream>>>(out, gsum1, gsq1, g1, be1);
}

// Round 4
// 356.298 us; speedup vs baseline: 2.4945x; 1.6516x over previous
//
#include <hip/hip_runtime.h>
#include <hip/hip_bf16.h>

typedef unsigned short u16;
typedef __attribute__((ext_vector_type(8))) __bf16 bf16x8;
typedef __attribute__((ext_vector_type(4))) float floatx4;

#define B_   16
#define N1_  4096
#define N2_  1024
#define C1_  128
#define C2_  256
#define CIN_ 384
#define CM_  256
#define CO_  128

__device__ __forceinline__ u16 f2bf(float f) {
  unsigned u = __float_as_uint(f);
  u = (u + 0x7fffu + ((u >> 16) & 1u)) >> 16;
  return (u16)u;
}
__device__ __forceinline__ float bf2f(u16 h) {
  return __uint_as_float(((unsigned)h) << 16);
}

union U128 { uint4 u; bf16x8 v; u16 s[8]; };

__device__ __forceinline__ bf16x8 ldfrag(const u16* p) {
  U128 x; x.u = *(const uint4*)p; return x.v;
}
__device__ __forceinline__ uint4 pack8(const u16* h) {
  uint4 u;
  u.x = (unsigned)h[0] | ((unsigned)h[1] << 16);
  u.y = (unsigned)h[2] | ((unsigned)h[3] << 16);
  u.z = (unsigned)h[4] | ((unsigned)h[5] << 16);
  u.w = (unsigned)h[6] | ((unsigned)h[7] << 16);
  return u;
}

// Tiled operand layout (MFMA-fragment-major):
//   frag(tile, kt) at [tile][kt][lane][8] u16, lane = quad*16+col,
//   element j = M[row=col][k = kt*32 + quad*8 + j]. Wave frag load = base + lane*16B.

// ---------------- K0: cast weights to bf16, tiled ----------------
__global__ __launch_bounds__(256) void castw_kernel(
    const float* __restrict__ w0, const float* __restrict__ w1,
    u16* __restrict__ w0b, u16* __restrict__ w1b)
{
  int i = blockIdx.x * 256 + threadIdx.x;          // 64 blocks = 16384 threads
  if (i < 12288) {                                  // w0: 256 rows x 48 chunks
    int m = i / 48, kc = i % 48;
    const float* p = w0 + m * CIN_ + kc * 8;
    u16 h8[8];
    #pragma unroll
    for (int j = 0; j < 8; ++j) h8[j] = f2bf(p[j]);
    int mt = m >> 4, col = m & 15, kt = kc >> 2, quad = kc & 3;
    *(uint4*)(w0b + ((mt*12 + kt)*512 + (quad*16 + col)*8)) = pack8(h8);
  } else {                                          // w1: 128 rows x 32 chunks
    int i2 = i - 12288;
    int m = i2 >> 5, kc = i2 & 31;
    const float* p = w1 + m * CM_ + kc * 8;
    u16 h8[8];
    #pragma unroll
    for (int j = 0; j < 8; ++j) h8[j] = f2bf(p[j]);
    int mt = m >> 4, col = m & 15, kt = kc >> 2, quad = kc & 3;
    *(uint4*)(w1b + ((mt*8 + kt)*512 + (quad*16 + col)*8)) = pack8(h8);
  }
}

// ---------------- K1: 3-NN ----------------
__global__ __launch_bounds__(256) void knn_kernel(
    const float* __restrict__ xyz1, const float* __restrict__ xyz2,
    int* __restrict__ idx_out, float* __restrict__ w_out)
{
  __shared__ float sx[N2_], sy[N2_], sz[N2_];
  int b = blockIdx.y;
  const float* p2 = xyz2 + b * N2_ * 3;
  for (int t = threadIdx.x; t < N2_; t += 256) {
    sx[t] = p2[t*3+0]; sy[t] = p2[t*3+1]; sz[t] = p2[t*3+2];
  }
  __syncthreads();
  int i = blockIdx.x * 256 + threadIdx.x;
  const float* p1 = xyz1 + (b * N1_ + i) * 3;
  float x = p1[0], y = p1[1], z = p1[2];
  float d0 = 1e30f, d1 = 1e30f, d2 = 1e30f;
  int i0 = 0, i1 = 0, i2 = 0;
  for (int j = 0; j < N2_; ++j) {
    float dx = x - sx[j], dy = y - sy[j], dz = z - sz[j];
    float d = dx*dx + dy*dy + dz*dz;
    if (d < d2) {
      if (d < d0)      { d2=d1; i2=i1; d1=d0; i1=i0; d0=d; i0=j; }
      else if (d < d1) { d2=d1; i2=i1; d1=d;  i1=j; }
      else             { d2=d;  i2=j; }
    }
  }
  float w0 = 1.f/(d0+1e-8f), w1 = 1.f/(d1+1e-8f), w2 = 1.f/(d2+1e-8f);
  float inv = 1.f/(w0+w1+w2);
  int base = b*N1_ + i;
  idx_out[base]            = i0;
  idx_out[base +   B_*N1_] = i1;
  idx_out[base + 2*B_*N1_] = i2;
  w_out[base]              = w0*inv;
  w_out[base +   B_*N1_]   = w1*inv;
  w_out[base + 2*B_*N1_]   = w2*inv;
}

// ---------------- K1.5: transpose feat2 -> feat2T[b][n2][c] fp32 ----------------
__global__ __launch_bounds__(256) void tr2_kernel(
    const float* __restrict__ feat2, float* __restrict__ feat2T)
{
  __shared__ float sA[64][257];
  int b = blockIdx.y;
  int n0 = blockIdx.x * 64;
  int t = threadIdx.x;
  #pragma unroll
  for (int j = 0; j < 16; ++j) {
    int flat4 = t + j * 256;                       // 4096 float4s: 256c x 64n
    int c = flat4 >> 4, nn4 = (flat4 & 15) * 4;
    float4 v = *(const float4*)(feat2 + ((size_t)b*C2_ + c)*N2_ + n0 + nn4);
    sA[nn4+0][c] = v.x; sA[nn4+1][c] = v.y; sA[nn4+2][c] = v.z; sA[nn4+3][c] = v.w;
  }
  __syncthreads();
  int nn = t & 63, chunk = t >> 6;
  float* dst = feat2T + ((size_t)b*N2_ + n0 + nn)*C2_ + chunk*64;
  #pragma unroll
  for (int g = 0; g < 16; ++g) {
    int c = chunk*64 + g*4;
    float4 v = make_float4(sA[nn][c], sA[nn][c+1], sA[nn][c+2], sA[nn][c+3]);
    *(float4*)(dst + g*4) = v;
  }
}

// ---------------- K2: build xcat tiled (feat1 transpose + 3NN interp) ----------------
__global__ __launch_bounds__(256) void prep_kernel(
    const float* __restrict__ feat1, const float* __restrict__ feat2T,
    const int* __restrict__ idx_in, const float* __restrict__ w_in,
    u16* __restrict__ xcatT)
{
  __shared__ float sA[64][133];
  int b = blockIdx.y;
  int n0 = blockIdx.x * 64;
  int t = threadIdx.x;
  #pragma unroll
  for (int j = 0; j < 8; ++j) {
    int flat4 = t + j * 256;                       // 2048 float4s: 128c x 64n
    int c = flat4 >> 4, nn4 = (flat4 & 15) * 4;
    float4 v = *(const float4*)(feat1 + ((size_t)b*C1_ + c)*N1_ + n0 + nn4);
    sA[nn4+0][c] = v.x; sA[nn4+1][c] = v.y; sA[nn4+2][c] = v.z; sA[nn4+3][c] = v.w;
  }
  __syncthreads();
  int nn = t & 63, chunk = t >> 6;
  int n = n0 + nn, nt = n >> 4, col = n & 15;
  u16* tb = xcatT + ((size_t)b*256 + nt)*12*512;
  #pragma unroll
  for (int g = 0; g < 4; ++g) {
    int c0 = chunk*32 + g*8;
    u16 h8[8];
    #pragma unroll
    for (int j = 0; j < 8; ++j) h8[j] = f2bf(sA[nn][c0 + j]);
    *(uint4*)(tb + (size_t)chunk*512 + (g*16 + col)*8) = pack8(h8);
  }
  int base = b*N1_ + n;
  int i0 = idx_in[base], i1 = idx_in[base + B_*N1_], i2 = idx_in[base + 2*B_*N1_];
  float w0 = w_in[base], w1 = w_in[base + B_*N1_], w2 = w_in[base + 2*B_*N1_];
  const float* r0 = feat2T + ((size_t)b*N2_ + i0)*C2_ + chunk*64;
  const float* r1 = feat2T + ((size_t)b*N2_ + i1)*C2_ + chunk*64;
  const float* r2 = feat2T + ((size_t)b*N2_ + i2)*C2_ + chunk*64;
  #pragma unroll
  for (int h = 0; h < 8; ++h) {
    float4 a0 = *(const float4*)(r0 + h*8),     a1 = *(const float4*)(r0 + h*8 + 4);
    float4 b0 = *(const float4*)(r1 + h*8),     b1 = *(const float4*)(r1 + h*8 + 4);
    float4 c0 = *(const float4*)(r2 + h*8),     c1 = *(const float4*)(r2 + h*8 + 4);
    u16 h8[8];
    h8[0] = f2bf(w0*a0.x + w1*b0.x + w2*c0.x);
    h8[1] = f2bf(w0*a0.y + w1*b0.y + w2*c0.y);
    h8[2] = f2bf(w0*a0.z + w1*b0.z + w2*c0.z);
    h8[3] = f2bf(w0*a0.w + w1*b0.w + w2*c0.w);
    h8[4] = f2bf(w0*a1.x + w1*b1.x + w2*c1.x);
    h8[5] = f2bf(w0*a1.y + w1*b1.y + w2*c1.y);
    h8[6] = f2bf(w0*a1.z + w1*b1.z + w2*c1.z);
    h8[7] = f2bf(w0*a1.w + w1*b1.w + w2*c1.w);
    int c = C1_ + chunk*64 + h*8;
    int kt = c >> 5, quad = (c >> 3) & 3;
    *(uint4*)(tb + (size_t)kt*512 + (quad*16 + col)*8) = pack8(h8);
  }
}

// ---------------- K3: GEMM1 MFMA, per-block partial stats (NO global atomics) ----------------
__global__ __launch_bounds__(256) void gemm1_mfma(
    const u16* __restrict__ xcatT, const u16* __restrict__ w0b,
    const float* __restrict__ b0p, u16* __restrict__ y0T,
    float* __restrict__ p0)
{
  __shared__ float ps[4][64][2];                   // [wave][ch64][sum|sq]
  int t = threadIdx.x;
  int wave = t >> 6, lane = t & 63;
  int col = lane & 15, quad = lane >> 4;
  int wm = wave >> 1, wn = wave & 1;
  int b = blockIdx.y;
  int mtb = blockIdx.z*8 + wm*4;
  int ntb = blockIdx.x*8 + wn*4;

  const u16* ap = w0b + lane*8;
  const u16* bp = xcatT + ((size_t)(b*256 + ntb)*12)*512 + lane*8;

  floatx4 acc[4][4] = {};
  bf16x8 af[4], bf[4], afn[4], bfn[4];
  #pragma unroll
  for (int i = 0; i < 4; ++i) {
    af[i] = ldfrag(ap + (size_t)((mtb+i)*12)*512);
    bf[i] = ldfrag(bp + (size_t)(i*12)*512);
  }
  #pragma unroll 1
  for (int kt = 1; kt < 12; ++kt) {
    #pragma unroll
    for (int i = 0; i < 4; ++i) afn[i] = ldfrag(ap + (size_t)((mtb+i)*12 + kt)*512);
    #pragma unroll
    for (int i = 0; i < 4; ++i) bfn[i] = ldfrag(bp + (size_t)(i*12 + kt)*512);
    #pragma unroll
    for (int mt = 0; mt < 4; ++mt)
      #pragma unroll
      for (int nt = 0; nt < 4; ++nt)
        acc[mt][nt] = __builtin_amdgcn_mfma_f32_16x16x32_bf16(af[mt], bf[nt], acc[mt][nt], 0, 0, 0);
    #pragma unroll
    for (int i = 0; i < 4; ++i) { af[i] = afn[i]; bf[i] = bfn[i]; }
  }
  #pragma unroll
  for (int mt = 0; mt < 4; ++mt)
    #pragma unroll
    for (int nt = 0; nt < 4; ++nt)
      acc[mt][nt] = __builtin_amdgcn_mfma_f32_16x16x32_bf16(af[mt], bf[nt], acc[mt][nt], 0, 0, 0);

  int m0 = blockIdx.z*128 + wm*64;
  #pragma unroll
  for (int mt = 0; mt < 4; ++mt) {
    float4 bias4 = *(const float4*)(b0p + m0 + mt*16 + quad*4);
    float bia[4] = {bias4.x, bias4.y, bias4.z, bias4.w};
    int kt_out = (m0 >> 5) + (mt >> 1);
    int quad_out = ((mt & 1) << 1) | (quad >> 1);
    int j0 = (quad & 1) * 4;
    float s[4] = {}, q[4] = {};
    #pragma unroll
    for (int nt = 0; nt < 4; ++nt) {
      int nt_g = ntb + nt;
      u16 h[4];
      #pragma unroll
      for (int r = 0; r < 4; ++r) {
        float v = acc[mt][nt][r] + bia[r];
        u16 hh = f2bf(v);
        float vr = bf2f(hh);
        h[r] = hh; s[r] += vr; q[r] += vr*vr;
      }
      *(ushort4*)(y0T + (((size_t)b*256 + nt_g)*8 + kt_out)*512 + (quad_out*16 + col)*8 + j0)
          = make_ushort4(h[0], h[1], h[2], h[3]);
    }
    #pragma unroll
    for (int r = 0; r < 4; ++r) {
      float ss = s[r], qq = q[r];
      #pragma unroll
      for (int msk = 1; msk < 16; msk <<= 1) { ss += __shfl_xor(ss, msk); qq += __shfl_xor(qq, msk); }
      if (col == 0) {
        ps[wave][mt*16 + quad*4 + r][0] = ss;
        ps[wave][mt*16 + quad*4 + r][1] = qq;
      }
    }
  }
  __syncthreads();
  // combine wave pairs, write 256-float partial (coalesced)
  {
    int c = t >> 1, k = t & 1;                     // c in [0,128)
    int wbase = (c >> 6) * 2, ch = c & 63;
    float v = ps[wbase][ch][k] + ps[wbase+1][ch][k];
    size_t l = (size_t)blockIdx.z*512 + blockIdx.y*32 + blockIdx.x;
    p0[l*256 + t] = v;
  }
}

// ---------------- K3.5: finalize stats -> scale/shift per channel ----------------
// grid.x = #channels. half_split=1: sources are the 512 blocks with z = c>>7 (gemm1).
__global__ __launch_bounds__(256) void stats_kernel(
    const float* __restrict__ p, const float* __restrict__ g,
    const float* __restrict__ be, float* __restrict__ scale,
    float* __restrict__ shift, int half_split)
{
  int c = blockIdx.x, t = threadIdx.x;
  size_t base = half_split ? ((size_t)(c >> 7) * 512 * 256 + (size_t)(c & 127) * 2)
                           : ((size_t)c * 2);
  float s = 0.f, q = 0.f;
  #pragma unroll
  for (int i = 0; i < 2; ++i) {
    float2 v = *(const float2*)(p + base + (size_t)(t + i*256) * 256);
    s += v.x; q += v.y;
  }
  #pragma unroll
  for (int m = 1; m < 64; m <<= 1) { s += __shfl_xor(s, m); q += __shfl_xor(q, m); }
  __shared__ float2 red[4];
  if ((t & 63) == 0) red[t >> 6] = make_float2(s, q);
  __syncthreads();
  if (t == 0) {
    float ss = red[0].x + red[1].x + red[2].x + red[3].x;
    float qq = red[0].y + red[1].y + red[2].y + red[3].y;
    float mu  = ss * (1.f/65536.f);
    float var = qq * (1.f/65536.f) - mu*mu;
    float a = g[c] * rsqrtf(var + 1e-5f);
    scale[c] = a; shift[c] = be[c] - mu*a;
  }
}

// ---------------- K4: GEMM2 MFMA, BN0+ReLU fused on B-load, partial stats ----------------
__global__ __launch_bounds__(256) void gemm2_mfma(
    const u16* __restrict__ y0T, const u16* __restrict__ w1b,
    const float* __restrict__ b1p,
    const float* __restrict__ scale0, const float* __restrict__ shift0,
    float* __restrict__ out, float* __restrict__ p1)
{
  __shared__ float a0s[CM_], bb0s[CM_];
  __shared__ float ps[4][64][2];
  int t = threadIdx.x;
  a0s[t] = scale0[t]; bb0s[t] = shift0[t];
  __syncthreads();
  int wave = t >> 6, lane = t & 63;
  int col = lane & 15, quad = lane >> 4;
  int wm = wave >> 1, wn = wave & 1;
  int b = blockIdx.y;
  int mtb = wm*4;
  int ntb = blockIdx.x*8 + wn*4;

  const u16* ap = w1b + lane*8;
  const u16* bp = y0T + ((size_t)(b*256 + ntb)*8)*512 + lane*8;

  floatx4 acc[4][4] = {};
  bf16x8 af[4], afn[4];
  U128 braw[4], brawn[4];
  #pragma unroll
  for (int i = 0; i < 4; ++i) {
    af[i] = ldfrag(ap + (size_t)((mtb+i)*8)*512);
    braw[i].u = *(const uint4*)(bp + (size_t)(i*8)*512);
  }
  #pragma unroll 1
  for (int kt = 1; kt < 8; ++kt) {
    #pragma unroll
    for (int i = 0; i < 4; ++i) afn[i] = ldfrag(ap + (size_t)((mtb+i)*8 + kt)*512);
    #pragma unroll
    for (int i = 0; i < 4; ++i) brawn[i].u = *(const uint4*)(bp + (size_t)(i*8 + kt)*512);
    int c0 = (kt-1)*32 + quad*8;
    float4 av0 = *(const float4*)&a0s[c0], av1 = *(const float4*)&a0s[c0+4];
    float4 bv0 = *(const float4*)&bb0s[c0], bv1 = *(const float4*)&bb0s[c0+4];
    float av[8] = {av0.x,av0.y,av0.z,av0.w,av1.x,av1.y,av1.z,av1.w};
    float bv[8] = {bv0.x,bv0.y,bv0.z,bv0.w,bv1.x,bv1.y,bv1.z,bv1.w};
    bf16x8 bfv[4];
    #pragma unroll
    for (int i = 0; i < 4; ++i) {
      u16 h8[8];
      #pragma unroll
      for (int j = 0; j < 8; ++j)
        h8[j] = f2bf(fmaxf(fmaf(bf2f(braw[i].s[j]), av[j], bv[j]), 0.f));
      U128 x; x.u = pack8(h8); bfv[i] = x.v;
    }
    #pragma unroll
    for (int mt = 0; mt < 4; ++mt)
      #pragma unroll
      for (int nt = 0; nt < 4; ++nt)
        acc[mt][nt] = __builtin_amdgcn_mfma_f32_16x16x32_bf16(af[mt], bfv[nt], acc[mt][nt], 0, 0, 0);
    #pragma unroll
    for (int i = 0; i < 4; ++i) { af[i] = afn[i]; braw[i] = brawn[i]; }
  }
  {
    int c0 = 7*32 + quad*8;
    float4 av0 = *(const float4*)&a0s[c0], av1 = *(const float4*)&a0s[c0+4];
    float4 bv0 = *(const float4*)&bb0s[c0], bv1 = *(const float4*)&bb0s[c0+4];
    float av[8] = {av0.x,av0.y,av0.z,av0.w,av1.x,av1.y,av1.z,av1.w};
    float bv[8] = {bv0.x,bv0.y,bv0.z,bv0.w,bv1.x,bv1.y,bv1.z,bv1.w};
    bf16x8 bfv[4];
    #pragma unroll
    for (int i = 0; i < 4; ++i) {
      u16 h8[8];
      #pragma unroll
      for (int j = 0; j < 8; ++j)
        h8[j] = f2bf(fmaxf(fmaf(bf2f(braw[i].s[j]), av[j], bv[j]), 0.f));
      U128 x; x.u = pack8(h8); bfv[i] = x.v;
    }
    #pragma unroll
    for (int mt = 0; mt < 4; ++mt)
      #pragma unroll
      for (int nt = 0; nt < 4; ++nt)
        acc[mt][nt] = __builtin_amdgcn_mfma_f32_16x16x32_bf16(af[mt], bfv[nt], acc[mt][nt], 0, 0, 0);
  }

  int m0 = wm*64;
  int n0 = blockIdx.x*128 + wn*64;
  #pragma unroll
  for (int mt = 0; mt < 4; ++mt) {
    float4 bias4 = *(const float4*)(b1p + m0 + mt*16 + quad*4);
    float bia[4] = {bias4.x, bias4.y, bias4.z, bias4.w};
    float s[4] = {}, q[4] = {};
    #pragma unroll
    for (int nt = 0; nt < 4; ++nt) {
      int n = n0 + nt*16 + col;
      #pragma unroll
      for (int r = 0; r < 4; ++r) {
        float v = acc[mt][nt][r] + bia[r];
        out[((size_t)b*CO_ + m0 + mt*16 + quad*4 + r)*N1_ + n] = v;
        s[r] += v; q[r] += v*v;
      }
    }
    #pragma unroll
    for (int r = 0; r < 4; ++r) {
      float ss = s[r], qq = q[r];
      #pragma unroll
      for (int msk = 1; msk < 16; msk <<= 1) { ss += __shfl_xor(ss, msk); qq += __shfl_xor(qq, msk); }
      if (col == 0) {
        ps[wave][mt*16 + quad*4 + r][0] = ss;
        ps[wave][mt*16 + quad*4 + r][1] = qq;
      }
    }
  }
  __syncthreads();
  {
    int c = t >> 1, k = t & 1;
    int wbase = (c >> 6) * 2, ch = c & 63;
    float v = ps[wbase][ch][k] + ps[wbase+1][ch][k];
    size_t l = (size_t)blockIdx.y*32 + blockIdx.x;
    p1[l*256 + t] = v;
  }
}

// ---------------- K5: BN1 + ReLU in place on d_out ----------------
__global__ __launch_bounds__(256) void bnrelu_kernel(
    float* __restrict__ out, const float* __restrict__ scale1, const float* __restrict__ shift1)
{
  int idx = blockIdx.x * 256 + threadIdx.x;   // float4 index
  int c = (idx >> 10) & (CO_ - 1);
  float a = scale1[c];
  float bb = shift1[c];
  float4 v = ((const float4*)out)[idx];
  v.x = fmaxf(fmaf(v.x, a, bb), 0.f);
  v.y = fmaxf(fmaf(v.y, a, bb), 0.f);
  v.z = fmaxf(fmaf(v.z, a, bb), 0.f);
  v.w = fmaxf(fmaf(v.w, a, bb), 0.f);
  ((float4*)out)[idx] = v;
}

extern "C" void kernel_launch(void* const* d_in, const int* in_sizes, int n_in,
                              void* d_out, int out_size, void* d_ws, size_t ws_size,
                              hipStream_t stream)
{
  const float* xyz1  = (const float*)d_in[0];
  const float* xyz2  = (const float*)d_in[1];
  const float* feat1 = (const float*)d_in[2];
  const float* feat2 = (const float*)d_in[3];
  const float* w0    = (const float*)d_in[4];
  const float* b0    = (const float*)d_in[5];
  const float* g0    = (const float*)d_in[6];
  const float* be0   = (const float*)d_in[7];
  const float* w1    = (const float*)d_in[8];
  const float* b1    = (const float*)d_in[9];
  const float* g1    = (const float*)d_in[10];
  const float* be1   = (const float*)d_in[11];
  float* out = (float*)d_out;
  char* ws = (char*)d_ws;

  // workspace layout (bytes) — feat2T aliases y0T (disjoint lifetimes)
  u16*   xcatT   = (u16*)ws;                                   // 50331648
  u16*   y0T     = (u16*)(ws + 50331648);                      // 33554432
  float* feat2T  = (float*)(ws + 50331648);                    // alias, used pre-gemm1
  u16*   w0b     = (u16*)(ws + 83886080);                      // 196608
  u16*   w1b     = (u16*)(ws + 84082688);                      // 65536
  int*   idx_buf = (int*)(ws + 84148224);                      // 786432
  float* w_buf   = (float*)(ws + 84934656);                    // 786432
  float* p0      = (float*)(ws + 85721088);                    // 1024*256*4 = 1048576
  float* p1      = (float*)(ws + 86769664);                    // 512*256*4  = 524288
  float* scale0  = (float*)(ws + 87293952);                    // 256
  float* shift0  = scale0 + 256;                               // 256
  float* scale1  = scale0 + 512;                               // 128
  float* shift1  = scale0 + 640;                               // 128

  castw_kernel<<<64,            256, 0, stream>>>(w0, w1, w0b, w1b);
  knn_kernel  <<<dim3(16,16),   256, 0, stream>>>(xyz1, xyz2, idx_buf, w_buf);
  tr2_kernel  <<<dim3(16,16),   256, 0, stream>>>(feat2, feat2T);
  prep_kernel <<<dim3(64,16),   256, 0, stream>>>(feat1, feat2T, idx_buf, w_buf, xcatT);
  gemm1_mfma  <<<dim3(32,16,2), 256, 0, stream>>>(xcatT, w0b, b0, y0T, p0);
  stats_kernel<<<256,           256, 0, stream>>>(p0, g0, be0, scale0, shift0, 1);
  gemm2_mfma  <<<dim3(32,16),   256, 0, stream>>>(y0T, w1b, b1, scale0, shift0, out, p1);
  stats_kernel<<<128,           256, 0, stream>>>(p1, g1, be1, scale1, shift1, 0);
  bnrelu_kernel<<<8192,         256, 0, stream>>>(out, scale1, shift1);
}

// Round 5
// 277.165 us; speedup vs baseline: 3.2067x; 1.2855x over previous
//
#include <hip/hip_runtime.h>
#include <hip/hip_bf16.h>

typedef unsigned short u16;
typedef __attribute__((ext_vector_type(8))) __bf16 bf16x8;
typedef __attribute__((ext_vector_type(4))) float floatx4;

#define B_   16
#define N1_  4096
#define N2_  1024
#define C1_  128
#define C2_  256
#define CIN_ 384
#define CM_  256
#define CO_  128

__device__ __forceinline__ u16 f2bf(float f) {
  unsigned u = __float_as_uint(f);
  u = (u + 0x7fffu + ((u >> 16) & 1u)) >> 16;
  return (u16)u;
}
__device__ __forceinline__ float bf2f(u16 h) {
  return __uint_as_float(((unsigned)h) << 16);
}

union U128 { uint4 u; bf16x8 v; u16 s[8]; };

__device__ __forceinline__ bf16x8 ldfrag(const u16* p) {
  U128 x; x.u = *(const uint4*)p; return x.v;
}
__device__ __forceinline__ uint4 pack8(const u16* h) {
  uint4 u;
  u.x = (unsigned)h[0] | ((unsigned)h[1] << 16);
  u.y = (unsigned)h[2] | ((unsigned)h[3] << 16);
  u.z = (unsigned)h[4] | ((unsigned)h[5] << 16);
  u.w = (unsigned)h[6] | ((unsigned)h[7] << 16);
  return u;
}

// Tiled operand layout (MFMA-fragment-major):
//   frag(tile, kt) at [tile][kt][lane][8] u16, lane = quad*16+col,
//   element j = M[row=col][k = kt*32 + quad*8 + j]. Wave frag load = base + lane*16B.

// ---------------- K0: cast weights to bf16, tiled ----------------
__global__ __launch_bounds__(256) void castw_kernel(
    const float* __restrict__ w0, const float* __restrict__ w1,
    u16* __restrict__ w0b, u16* __restrict__ w1b)
{
  int i = blockIdx.x * 256 + threadIdx.x;          // 64 blocks = 16384 threads
  if (i < 12288) {                                  // w0: 256 rows x 48 chunks
    int m = i / 48, kc = i % 48;
    const float* p = w0 + m * CIN_ + kc * 8;
    u16 h8[8];
    #pragma unroll
    for (int j = 0; j < 8; ++j) h8[j] = f2bf(p[j]);
    int mt = m >> 4, col = m & 15, kt = kc >> 2, quad = kc & 3;
    *(uint4*)(w0b + ((mt*12 + kt)*512 + (quad*16 + col)*8)) = pack8(h8);
  } else {                                          // w1: 128 rows x 32 chunks
    int i2 = i - 12288;
    int m = i2 >> 5, kc = i2 & 31;
    const float* p = w1 + m * CM_ + kc * 8;
    u16 h8[8];
    #pragma unroll
    for (int j = 0; j < 8; ++j) h8[j] = f2bf(p[j]);
    int mt = m >> 4, col = m & 15, kt = kc >> 2, quad = kc & 3;
    *(uint4*)(w1b + ((mt*8 + kt)*512 + (quad*16 + col)*8)) = pack8(h8);
  }
}

// ---------------- K1a: 3-NN partial over a 256-j chunk ----------------
__global__ __launch_bounds__(256) void knn_part_kernel(
    const float* __restrict__ xyz1, const float* __restrict__ xyz2,
    float* __restrict__ pd, int* __restrict__ pi)
{
  __shared__ float4 sp[256];
  int b = blockIdx.y;
  int chunk = blockIdx.z;
  int t = threadIdx.x;
  const float* p2 = xyz2 + ((size_t)b * N2_ + chunk * 256) * 3;
  sp[t] = make_float4(p2[t*3], p2[t*3+1], p2[t*3+2], 0.f);
  __syncthreads();
  int i = blockIdx.x * 256 + t;
  const float* p1 = xyz1 + ((size_t)b * N1_ + i) * 3;
  float x = p1[0], y = p1[1], z = p1[2];
  float d0 = 1e30f, d1 = 1e30f, d2 = 1e30f;
  int i0 = 0, i1 = 0, i2 = 0;
  int jbase = chunk * 256;
  #pragma unroll 4
  for (int j = 0; j < 256; ++j) {
    float4 p = sp[j];                              // broadcast b128: conflict-free
    float dx = x - p.x, dy = y - p.y, dz = z - p.z;
    float d = dx*dx + dy*dy + dz*dz;
    if (d < d2) {                                  // strict <: stable (earlier j wins ties)
      if (d < d0)      { d2=d1; i2=i1; d1=d0; i1=i0; d0=d; i0=jbase+j; }
      else if (d < d1) { d2=d1; i2=i1; d1=d;  i1=jbase+j; }
      else             { d2=d;  i2=jbase+j; }
    }
  }
  int o = chunk*65536 + b*4096 + i;
  pd[o] = d0; pd[o + 262144] = d1; pd[o + 524288] = d2;
  pi[o] = i0; pi[o + 262144] = i1; pi[o + 524288] = i2;
}

// ---------------- K1b: merge 4 chunk-triples -> final idx/weights ----------------
__global__ __launch_bounds__(256) void knn_merge_kernel(
    const float* __restrict__ pd, const int* __restrict__ pi,
    int* __restrict__ idx_out, float* __restrict__ w_out)
{
  int p = blockIdx.x * 256 + threadIdx.x;          // p = b*4096 + i, 0..65535
  float d0 = 1e30f, d1 = 1e30f, d2 = 1e30f;
  int i0 = 0, i1 = 0, i2 = 0;
  #pragma unroll
  for (int c = 0; c < 4; ++c) {                    // ascending-j chunk order: stable
    int o = c*65536 + p;
    #pragma unroll
    for (int k = 0; k < 3; ++k) {
      float d = pd[o + k*262144];
      int ix = pi[o + k*262144];
      if (d < d2) {
        if (d < d0)      { d2=d1; i2=i1; d1=d0; i1=i0; d0=d; i0=ix; }
        else if (d < d1) { d2=d1; i2=i1; d1=d;  i1=ix; }
        else             { d2=d;  i2=ix; }
      }
    }
  }
  float w0 = 1.f/(d0+1e-8f), w1 = 1.f/(d1+1e-8f), w2 = 1.f/(d2+1e-8f);
  float inv = 1.f/(w0+w1+w2);
  idx_out[p]          = i0;
  idx_out[p +  65536] = i1;
  idx_out[p + 131072] = i2;
  w_out[p]            = w0*inv;
  w_out[p +  65536]   = w1*inv;
  w_out[p + 131072]   = w2*inv;
}

// ---------------- K1.5: transpose feat2 -> feat2T[b][n2][c] fp32 ----------------
__global__ __launch_bounds__(256) void tr2_kernel(
    const float* __restrict__ feat2, float* __restrict__ feat2T)
{
  __shared__ float sA[64][257];
  int b = blockIdx.y;
  int n0 = blockIdx.x * 64;
  int t = threadIdx.x;
  #pragma unroll
  for (int j = 0; j < 16; ++j) {
    int flat4 = t + j * 256;                       // 4096 float4s: 256c x 64n
    int c = flat4 >> 4, nn4 = (flat4 & 15) * 4;
    float4 v = *(const float4*)(feat2 + ((size_t)b*C2_ + c)*N2_ + n0 + nn4);
    sA[nn4+0][c] = v.x; sA[nn4+1][c] = v.y; sA[nn4+2][c] = v.z; sA[nn4+3][c] = v.w;
  }
  __syncthreads();
  int nn = t & 63, chunk = t >> 6;
  float* dst = feat2T + ((size_t)b*N2_ + n0 + nn)*C2_ + chunk*64;
  #pragma unroll
  for (int g = 0; g < 16; ++g) {
    int c = chunk*64 + g*4;
    float4 v = make_float4(sA[nn][c], sA[nn][c+1], sA[nn][c+2], sA[nn][c+3]);
    *(float4*)(dst + g*4) = v;
  }
}

// ---------------- K2: build xcat tiled (feat1 transpose + 3NN interp) ----------------
__global__ __launch_bounds__(256) void prep_kernel(
    const float* __restrict__ feat1, const float* __restrict__ feat2T,
    const int* __restrict__ idx_in, const float* __restrict__ w_in,
    u16* __restrict__ xcatT)
{
  __shared__ float sA[64][133];
  int b = blockIdx.y;
  int n0 = blockIdx.x * 64;
  int t = threadIdx.x;
  #pragma unroll
  for (int j = 0; j < 8; ++j) {
    int flat4 = t + j * 256;                       // 2048 float4s: 128c x 64n
    int c = flat4 >> 4, nn4 = (flat4 & 15) * 4;
    float4 v = *(const float4*)(feat1 + ((size_t)b*C1_ + c)*N1_ + n0 + nn4);
    sA[nn4+0][c] = v.x; sA[nn4+1][c] = v.y; sA[nn4+2][c] = v.z; sA[nn4+3][c] = v.w;
  }
  __syncthreads();
  int nn = t & 63, chunk = t >> 6;
  int n = n0 + nn, nt = n >> 4, col = n & 15;
  u16* tb = xcatT + ((size_t)b*256 + nt)*12*512;
  #pragma unroll
  for (int g = 0; g < 4; ++g) {
    int c0 = chunk*32 + g*8;
    u16 h8[8];
    #pragma unroll
    for (int j = 0; j < 8; ++j) h8[j] = f2bf(sA[nn][c0 + j]);
    *(uint4*)(tb + (size_t)chunk*512 + (g*16 + col)*8) = pack8(h8);
  }
  int base = b*N1_ + n;
  int i0 = idx_in[base], i1 = idx_in[base + B_*N1_], i2 = idx_in[base + 2*B_*N1_];
  float w0 = w_in[base], w1 = w_in[base + B_*N1_], w2 = w_in[base + 2*B_*N1_];
  const float* r0 = feat2T + ((size_t)b*N2_ + i0)*C2_ + chunk*64;
  const float* r1 = feat2T + ((size_t)b*N2_ + i1)*C2_ + chunk*64;
  const float* r2 = feat2T + ((size_t)b*N2_ + i2)*C2_ + chunk*64;
  #pragma unroll
  for (int h = 0; h < 8; ++h) {
    float4 a0 = *(const float4*)(r0 + h*8),     a1 = *(const float4*)(r0 + h*8 + 4);
    float4 b0 = *(const float4*)(r1 + h*8),     b1 = *(const float4*)(r1 + h*8 + 4);
    float4 c0 = *(const float4*)(r2 + h*8),     c1 = *(const float4*)(r2 + h*8 + 4);
    u16 h8[8];
    h8[0] = f2bf(w0*a0.x + w1*b0.x + w2*c0.x);
    h8[1] = f2bf(w0*a0.y + w1*b0.y + w2*c0.y);
    h8[2] = f2bf(w0*a0.z + w1*b0.z + w2*c0.z);
    h8[3] = f2bf(w0*a0.w + w1*b0.w + w2*c0.w);
    h8[4] = f2bf(w0*a1.x + w1*b1.x + w2*c1.x);
    h8[5] = f2bf(w0*a1.y + w1*b1.y + w2*c1.y);
    h8[6] = f2bf(w0*a1.z + w1*b1.z + w2*c1.z);
    h8[7] = f2bf(w0*a1.w + w1*b1.w + w2*c1.w);
    int c = C1_ + chunk*64 + h*8;
    int kt = c >> 5, quad = (c >> 3) & 3;
    *(uint4*)(tb + (size_t)kt*512 + (quad*16 + col)*8) = pack8(h8);
  }
}

// ---------------- K3: GEMM1 MFMA, per-block partial stats (NO global atomics) ----------------
__global__ __launch_bounds__(256) void gemm1_mfma(
    const u16* __restrict__ xcatT, const u16* __restrict__ w0b,
    const float* __restrict__ b0p, u16* __restrict__ y0T,
    float* __restrict__ p0)
{
  __shared__ float ps[4][64][2];                   // [wave][ch64][sum|sq]
  int t = threadIdx.x;
  int wave = t >> 6, lane = t & 63;
  int col = lane & 15, quad = lane >> 4;
  int wm = wave >> 1, wn = wave & 1;
  int b = blockIdx.y;
  int mtb = blockIdx.z*8 + wm*4;
  int ntb = blockIdx.x*8 + wn*4;

  const u16* ap = w0b + lane*8;
  const u16* bp = xcatT + ((size_t)(b*256 + ntb)*12)*512 + lane*8;

  floatx4 acc[4][4] = {};
  bf16x8 af[4], bf[4], afn[4], bfn[4];
  #pragma unroll
  for (int i = 0; i < 4; ++i) {
    af[i] = ldfrag(ap + (size_t)((mtb+i)*12)*512);
    bf[i] = ldfrag(bp + (size_t)(i*12)*512);
  }
  #pragma unroll 1
  for (int kt = 1; kt < 12; ++kt) {
    #pragma unroll
    for (int i = 0; i < 4; ++i) afn[i] = ldfrag(ap + (size_t)((mtb+i)*12 + kt)*512);
    #pragma unroll
    for (int i = 0; i < 4; ++i) bfn[i] = ldfrag(bp + (size_t)(i*12 + kt)*512);
    #pragma unroll
    for (int mt = 0; mt < 4; ++mt)
      #pragma unroll
      for (int nt = 0; nt < 4; ++nt)
        acc[mt][nt] = __builtin_amdgcn_mfma_f32_16x16x32_bf16(af[mt], bf[nt], acc[mt][nt], 0, 0, 0);
    #pragma unroll
    for (int i = 0; i < 4; ++i) { af[i] = afn[i]; bf[i] = bfn[i]; }
  }
  #pragma unroll
  for (int mt = 0; mt < 4; ++mt)
    #pragma unroll
    for (int nt = 0; nt < 4; ++nt)
      acc[mt][nt] = __builtin_amdgcn_mfma_f32_16x16x32_bf16(af[mt], bf[nt], acc[mt][nt], 0, 0, 0);

  int m0 = blockIdx.z*128 + wm*64;
  #pragma unroll
  for (int mt = 0; mt < 4; ++mt) {
    float4 bias4 = *(const float4*)(b0p + m0 + mt*16 + quad*4);
    float bia[4] = {bias4.x, bias4.y, bias4.z, bias4.w};
    int kt_out = (m0 >> 5) + (mt >> 1);
    int quad_out = ((mt & 1) << 1) | (quad >> 1);
    int j0 = (quad & 1) * 4;
    float s[4] = {}, q[4] = {};
    #pragma unroll
    for (int nt = 0; nt < 4; ++nt) {
      int nt_g = ntb + nt;
      u16 h[4];
      #pragma unroll
      for (int r = 0; r < 4; ++r) {
        float v = acc[mt][nt][r] + bia[r];
        u16 hh = f2bf(v);
        float vr = bf2f(hh);
        h[r] = hh; s[r] += vr; q[r] += vr*vr;
      }
      *(ushort4*)(y0T + (((size_t)b*256 + nt_g)*8 + kt_out)*512 + (quad_out*16 + col)*8 + j0)
          = make_ushort4(h[0], h[1], h[2], h[3]);
    }
    #pragma unroll
    for (int r = 0; r < 4; ++r) {
      float ss = s[r], qq = q[r];
      #pragma unroll
      for (int msk = 1; msk < 16; msk <<= 1) { ss += __shfl_xor(ss, msk); qq += __shfl_xor(qq, msk); }
      if (col == 0) {
        ps[wave][mt*16 + quad*4 + r][0] = ss;
        ps[wave][mt*16 + quad*4 + r][1] = qq;
      }
    }
  }
  __syncthreads();
  {
    int c = t >> 1, k = t & 1;                     // c in [0,128)
    int wbase = (c >> 6) * 2, ch = c & 63;
    float v = ps[wbase][ch][k] + ps[wbase+1][ch][k];
    size_t l = (size_t)blockIdx.z*512 + blockIdx.y*32 + blockIdx.x;
    p0[l*256 + t] = v;
  }
}

// ---------------- K3.5: finalize stats -> scale/shift per channel ----------------
__global__ __launch_bounds__(256) void stats_kernel(
    const float* __restrict__ p, const float* __restrict__ g,
    const float* __restrict__ be, float* __restrict__ scale,
    float* __restrict__ shift, int half_split)
{
  int c = blockIdx.x, t = threadIdx.x;
  size_t base = half_split ? ((size_t)(c >> 7) * 512 * 256 + (size_t)(c & 127) * 2)
                           : ((size_t)c * 2);
  float s = 0.f, q = 0.f;
  #pragma unroll
  for (int i = 0; i < 2; ++i) {
    float2 v = *(const float2*)(p + base + (size_t)(t + i*256) * 256);
    s += v.x; q += v.y;
  }
  #pragma unroll
  for (int m = 1; m < 64; m <<= 1) { s += __shfl_xor(s, m); q += __shfl_xor(q, m); }
  __shared__ float2 red[4];
  if ((t & 63) == 0) red[t >> 6] = make_float2(s, q);
  __syncthreads();
  if (t == 0) {
    float ss = red[0].x + red[1].x + red[2].x + red[3].x;
    float qq = red[0].y + red[1].y + red[2].y + red[3].y;
    float mu  = ss * (1.f/65536.f);
    float var = qq * (1.f/65536.f) - mu*mu;
    float a = g[c] * rsqrtf(var + 1e-5f);
    scale[c] = a; shift[c] = be[c] - mu*a;
  }
}

// ---------------- K4: GEMM2 MFMA, BN0+ReLU fused on B-load, partial stats ----------------
__global__ __launch_bounds__(256) void gemm2_mfma(
    const u16* __restrict__ y0T, const u16* __restrict__ w1b,
    const float* __restrict__ b1p,
    const float* __restrict__ scale0, const float* __restrict__ shift0,
    float* __restrict__ out, float* __restrict__ p1)
{
  __shared__ float a0s[CM_], bb0s[CM_];
  __shared__ float ps[4][64][2];
  int t = threadIdx.x;
  a0s[t] = scale0[t]; bb0s[t] = shift0[t];
  __syncthreads();
  int wave = t >> 6, lane = t & 63;
  int col = lane & 15, quad = lane >> 4;
  int wm = wave >> 1, wn = wave & 1;
  int b = blockIdx.y;
  int mtb = wm*4;
  int ntb = blockIdx.x*8 + wn*4;

  const u16* ap = w1b + lane*8;
  const u16* bp = y0T + ((size_t)(b*256 + ntb)*8)*512 + lane*8;

  floatx4 acc[4][4] = {};
  bf16x8 af[4], afn[4];
  U128 braw[4], brawn[4];
  #pragma unroll
  for (int i = 0; i < 4; ++i) {
    af[i] = ldfrag(ap + (size_t)((mtb+i)*8)*512);
    braw[i].u = *(const uint4*)(bp + (size_t)(i*8)*512);
  }
  #pragma unroll 1
  for (int kt = 1; kt < 8; ++kt) {
    #pragma unroll
    for (int i = 0; i < 4; ++i) afn[i] = ldfrag(ap + (size_t)((mtb+i)*8 + kt)*512);
    #pragma unroll
    for (int i = 0; i < 4; ++i) brawn[i].u = *(const uint4*)(bp + (size_t)(i*8 + kt)*512);
    int c0 = (kt-1)*32 + quad*8;
    float4 av0 = *(const float4*)&a0s[c0], av1 = *(const float4*)&a0s[c0+4];
    float4 bv0 = *(const float4*)&bb0s[c0], bv1 = *(const float4*)&bb0s[c0+4];
    float av[8] = {av0.x,av0.y,av0.z,av0.w,av1.x,av1.y,av1.z,av1.w};
    float bv[8] = {bv0.x,bv0.y,bv0.z,bv0.w,bv1.x,bv1.y,bv1.z,bv1.w};
    bf16x8 bfv[4];
    #pragma unroll
    for (int i = 0; i < 4; ++i) {
      u16 h8[8];
      #pragma unroll
      for (int j = 0; j < 8; ++j)
        h8[j] = f2bf(fmaxf(fmaf(bf2f(braw[i].s[j]), av[j], bv[j]), 0.f));
      U128 x; x.u = pack8(h8); bfv[i] = x.v;
    }
    #pragma unroll
    for (int mt = 0; mt < 4; ++mt)
      #pragma unroll
      for (int nt = 0; nt < 4; ++nt)
        acc[mt][nt] = __builtin_amdgcn_mfma_f32_16x16x32_bf16(af[mt], bfv[nt], acc[mt][nt], 0, 0, 0);
    #pragma unroll
    for (int i = 0; i < 4; ++i) { af[i] = afn[i]; braw[i] = brawn[i]; }
  }
  {
    int c0 = 7*32 + quad*8;
    float4 av0 = *(const float4*)&a0s[c0], av1 = *(const float4*)&a0s[c0+4];
    float4 bv0 = *(const float4*)&bb0s[c0], bv1 = *(const float4*)&bb0s[c0+4];
    float av[8] = {av0.x,av0.y,av0.z,av0.w,av1.x,av1.y,av1.z,av1.w};
    float bv[8] = {bv0.x,bv0.y,bv0.z,bv0.w,bv1.x,bv1.y,bv1.z,bv1.w};
    bf16x8 bfv[4];
    #pragma unroll
    for (int i = 0; i < 4; ++i) {
      u16 h8[8];
      #pragma unroll
      for (int j = 0; j < 8; ++j)
        h8[j] = f2bf(fmaxf(fmaf(bf2f(braw[i].s[j]), av[j], bv[j]), 0.f));
      U128 x; x.u = pack8(h8); bfv[i] = x.v;
    }
    #pragma unroll
    for (int mt = 0; mt < 4; ++mt)
      #pragma unroll
      for (int nt = 0; nt < 4; ++nt)
        acc[mt][nt] = __builtin_amdgcn_mfma_f32_16x16x32_bf16(af[mt], bfv[nt], acc[mt][nt], 0, 0, 0);
  }

  int m0 = wm*64;
  int n0 = blockIdx.x*128 + wn*64;
  #pragma unroll
  for (int mt = 0; mt < 4; ++mt) {
    float4 bias4 = *(const float4*)(b1p + m0 + mt*16 + quad*4);
    float bia[4] = {bias4.x, bias4.y, bias4.z, bias4.w};
    float s[4] = {}, q[4] = {};
    #pragma unroll
    for (int nt = 0; nt < 4; ++nt) {
      int n = n0 + nt*16 + col;
      #pragma unroll
      for (int r = 0; r < 4; ++r) {
        float v = acc[mt][nt][r] + bia[r];
        out[((size_t)b*CO_ + m0 + mt*16 + quad*4 + r)*N1_ + n] = v;
        s[r] += v; q[r] += v*v;
      }
    }
    #pragma unroll
    for (int r = 0; r < 4; ++r) {
      float ss = s[r], qq = q[r];
      #pragma unroll
      for (int msk = 1; msk < 16; msk <<= 1) { ss += __shfl_xor(ss, msk); qq += __shfl_xor(qq, msk); }
      if (col == 0) {
        ps[wave][mt*16 + quad*4 + r][0] = ss;
        ps[wave][mt*16 + quad*4 + r][1] = qq;
      }
    }
  }
  __syncthreads();
  {
    int c = t >> 1, k = t & 1;
    int wbase = (c >> 6) * 2, ch = c & 63;
    float v = ps[wbase][ch][k] + ps[wbase+1][ch][k];
    size_t l = (size_t)blockIdx.y*32 + blockIdx.x;
    p1[l*256 + t] = v;
  }
}

// ---------------- K5: BN1 + ReLU in place on d_out ----------------
__global__ __launch_bounds__(256) void bnrelu_kernel(
    float* __restrict__ out, const float* __restrict__ scale1, const float* __restrict__ shift1)
{
  int idx = blockIdx.x * 256 + threadIdx.x;   // float4 index
  int c = (idx >> 10) & (CO_ - 1);
  float a = scale1[c];
  float bb = shift1[c];
  float4 v = ((const float4*)out)[idx];
  v.x = fmaxf(fmaf(v.x, a, bb), 0.f);
  v.y = fmaxf(fmaf(v.y, a, bb), 0.f);
  v.z = fmaxf(fmaf(v.z, a, bb), 0.f);
  v.w = fmaxf(fmaf(v.w, a, bb), 0.f);
  ((float4*)out)[idx] = v;
}

extern "C" void kernel_launch(void* const* d_in, const int* in_sizes, int n_in,
                              void* d_out, int out_size, void* d_ws, size_t ws_size,
                              hipStream_t stream)
{
  const float* xyz1  = (const float*)d_in[0];
  const float* xyz2  = (const float*)d_in[1];
  const float* feat1 = (const float*)d_in[2];
  const float* feat2 = (const float*)d_in[3];
  const float* w0    = (const float*)d_in[4];
  const float* b0    = (const float*)d_in[5];
  const float* g0    = (const float*)d_in[6];
  const float* be0   = (const float*)d_in[7];
  const float* w1    = (const float*)d_in[8];
  const float* b1    = (const float*)d_in[9];
  const float* g1    = (const float*)d_in[10];
  const float* be1   = (const float*)d_in[11];
  float* out = (float*)d_out;
  char* ws = (char*)d_ws;

  // workspace layout (bytes)
  u16*   xcatT   = (u16*)ws;                                   // 50331648
  float* knn_pd  = (float*)ws;                                 // 3*1 MB (alias xcatT; dead before prep)
  int*   knn_pi  = (int*)(ws + 3145728);                       // 3*1 MB
  u16*   y0T     = (u16*)(ws + 50331648);                      // 33554432
  float* feat2T  = (float*)(ws + 50331648);                    // alias, used pre-gemm1
  u16*   w0b     = (u16*)(ws + 83886080);                      // 196608
  u16*   w1b     = (u16*)(ws + 84082688);                      // 65536
  int*   idx_buf = (int*)(ws + 84148224);                      // 786432
  float* w_buf   = (float*)(ws + 84934656);                    // 786432
  float* p0      = (float*)(ws + 85721088);                    // 1048576
  float* p1      = (float*)(ws + 86769664);                    // 524288
  float* scale0  = (float*)(ws + 87293952);                    // 256
  float* shift0  = scale0 + 256;
  float* scale1  = scale0 + 512;
  float* shift1  = scale0 + 640;

  castw_kernel   <<<64,              256, 0, stream>>>(w0, w1, w0b, w1b);
  knn_part_kernel<<<dim3(16,16,4),   256, 0, stream>>>(xyz1, xyz2, knn_pd, knn_pi);
  knn_merge_kernel<<<256,            256, 0, stream>>>(knn_pd, knn_pi, idx_buf, w_buf);
  tr2_kernel     <<<dim3(16,16),     256, 0, stream>>>(feat2, feat2T);
  prep_kernel    <<<dim3(64,16),     256, 0, stream>>>(feat1, feat2T, idx_buf, w_buf, xcatT);
  gemm1_mfma     <<<dim3(32,16,2),   256, 0, stream>>>(xcatT, w0b, b0, y0T, p0);
  stats_kernel   <<<256,             256, 0, stream>>>(p0, g0, be0, scale0, shift0, 1);
  gemm2_mfma     <<<dim3(32,16),     256, 0, stream>>>(y0T, w1b, b1, scale0, shift0, out, p1);
  stats_kernel   <<<128,             256, 0, stream>>>(p1, g1, be1, scale1, shift1, 0);
  bnrelu_kernel  <<<8192,            256, 0, stream>>>(out, scale1, shift1);
}

// Round 6
// 251.720 us; speedup vs baseline: 3.5309x; 1.1011x over previous
//
#include <hip/hip_runtime.h>
#include <hip/hip_bf16.h>

typedef unsigned short u16;
typedef __attribute__((ext_vector_type(8))) __bf16 bf16x8;
typedef __attribute__((ext_vector_type(4))) float floatx4;

#define B_   16
#define N1_  4096
#define N2_  1024
#define C1_  128
#define C2_  256
#define CIN_ 384
#define CM_  256
#define CO_  128

__device__ __forceinline__ u16 f2bf(float f) {
  unsigned u = __float_as_uint(f);
  u = (u + 0x7fffu + ((u >> 16) & 1u)) >> 16;
  return (u16)u;
}
__device__ __forceinline__ float bf2f(u16 h) {
  return __uint_as_float(((unsigned)h) << 16);
}

union U128 { uint4 u; bf16x8 v; u16 s[8]; };

__device__ __forceinline__ bf16x8 ldfrag(const u16* p) {
  U128 x; x.u = *(const uint4*)p; return x.v;
}
__device__ __forceinline__ uint4 pack8(const u16* h) {
  uint4 u;
  u.x = (unsigned)h[0] | ((unsigned)h[1] << 16);
  u.y = (unsigned)h[2] | ((unsigned)h[3] << 16);
  u.z = (unsigned)h[4] | ((unsigned)h[5] << 16);
  u.w = (unsigned)h[6] | ((unsigned)h[7] << 16);
  return u;
}

// Tiled operand layout (MFMA-fragment-major):
//   frag(tile, kt) at [tile][kt][lane][8] u16, lane = quad*16+col,
//   element j = M[row=col][k = kt*32 + quad*8 + j]. Wave frag load = base + lane*16B.

// ---------------- K0: cast weights to bf16, tiled ----------------
__global__ __launch_bounds__(256) void castw_kernel(
    const float* __restrict__ w0, const float* __restrict__ w1,
    u16* __restrict__ w0b, u16* __restrict__ w1b)
{
  int i = blockIdx.x * 256 + threadIdx.x;          // 64 blocks = 16384 threads
  if (i < 12288) {                                  // w0: 256 rows x 48 chunks
    int m = i / 48, kc = i % 48;
    const float* p = w0 + m * CIN_ + kc * 8;
    u16 h8[8];
    #pragma unroll
    for (int j = 0; j < 8; ++j) h8[j] = f2bf(p[j]);
    int mt = m >> 4, col = m & 15, kt = kc >> 2, quad = kc & 3;
    *(uint4*)(w0b + ((mt*12 + kt)*512 + (quad*16 + col)*8)) = pack8(h8);
  } else {                                          // w1: 128 rows x 32 chunks
    int i2 = i - 12288;
    int m = i2 >> 5, kc = i2 & 31;
    const float* p = w1 + m * CM_ + kc * 8;
    u16 h8[8];
    #pragma unroll
    for (int j = 0; j < 8; ++j) h8[j] = f2bf(p[j]);
    int mt = m >> 4, col = m & 15, kt = kc >> 2, quad = kc & 3;
    *(uint4*)(w1b + ((mt*8 + kt)*512 + (quad*16 + col)*8)) = pack8(h8);
  }
}

// ---------------- K1a: 3-NN partial over a 256-j chunk ----------------
__global__ __launch_bounds__(256) void knn_part_kernel(
    const float* __restrict__ xyz1, const float* __restrict__ xyz2,
    float* __restrict__ pd, int* __restrict__ pi)
{
  __shared__ float4 sp[256];
  int b = blockIdx.y;
  int chunk = blockIdx.z;
  int t = threadIdx.x;
  const float* p2 = xyz2 + ((size_t)b * N2_ + chunk * 256) * 3;
  sp[t] = make_float4(p2[t*3], p2[t*3+1], p2[t*3+2], 0.f);
  __syncthreads();
  int i = blockIdx.x * 256 + t;
  const float* p1 = xyz1 + ((size_t)b * N1_ + i) * 3;
  float x = p1[0], y = p1[1], z = p1[2];
  float d0 = 1e30f, d1 = 1e30f, d2 = 1e30f;
  int i0 = 0, i1 = 0, i2 = 0;
  int jbase = chunk * 256;
  #pragma unroll 4
  for (int j = 0; j < 256; ++j) {
    float4 p = sp[j];                              // broadcast b128: conflict-free
    float dx = x - p.x, dy = y - p.y, dz = z - p.z;
    float d = dx*dx + dy*dy + dz*dz;
    if (d < d2) {                                  // strict <: stable (earlier j wins ties)
      if (d < d0)      { d2=d1; i2=i1; d1=d0; i1=i0; d0=d; i0=jbase+j; }
      else if (d < d1) { d2=d1; i2=i1; d1=d;  i1=jbase+j; }
      else             { d2=d;  i2=jbase+j; }
    }
  }
  int o = chunk*65536 + b*4096 + i;
  pd[o] = d0; pd[o + 262144] = d1; pd[o + 524288] = d2;
  pi[o] = i0; pi[o + 262144] = i1; pi[o + 524288] = i2;
}

// ---------------- K1b: merge 4 chunk-triples -> final idx/weights ----------------
__global__ __launch_bounds__(256) void knn_merge_kernel(
    const float* __restrict__ pd, const int* __restrict__ pi,
    int* __restrict__ idx_out, float* __restrict__ w_out)
{
  int p = blockIdx.x * 256 + threadIdx.x;          // p = b*4096 + i, 0..65535
  float d0 = 1e30f, d1 = 1e30f, d2 = 1e30f;
  int i0 = 0, i1 = 0, i2 = 0;
  #pragma unroll
  for (int c = 0; c < 4; ++c) {                    // ascending-j chunk order: stable
    int o = c*65536 + p;
    #pragma unroll
    for (int k = 0; k < 3; ++k) {
      float d = pd[o + k*262144];
      int ix = pi[o + k*262144];
      if (d < d2) {
        if (d < d0)      { d2=d1; i2=i1; d1=d0; i1=i0; d0=d; i0=ix; }
        else if (d < d1) { d2=d1; i2=i1; d1=d;  i1=ix; }
        else             { d2=d;  i2=ix; }
      }
    }
  }
  float w0 = 1.f/(d0+1e-8f), w1 = 1.f/(d1+1e-8f), w2 = 1.f/(d2+1e-8f);
  float inv = 1.f/(w0+w1+w2);
  idx_out[p]          = i0;
  idx_out[p +  65536] = i1;
  idx_out[p + 131072] = i2;
  w_out[p]            = w0*inv;
  w_out[p +  65536]   = w1*inv;
  w_out[p + 131072]   = w2*inv;
}

// ---------------- K1.5: transpose feat2 -> feat2Tb[b][n2][c] bf16 ----------------
__global__ __launch_bounds__(256) void tr2_kernel(
    const float* __restrict__ feat2, u16* __restrict__ feat2Tb)
{
  __shared__ float sA[64][257];
  int b = blockIdx.y;
  int n0 = blockIdx.x * 64;
  int t = threadIdx.x;
  #pragma unroll
  for (int j = 0; j < 16; ++j) {
    int flat4 = t + j * 256;                       // 4096 float4s: 256c x 64n
    int c = flat4 >> 4, nn4 = (flat4 & 15) * 4;
    float4 v = *(const float4*)(feat2 + ((size_t)b*C2_ + c)*N2_ + n0 + nn4);
    sA[nn4+0][c] = v.x; sA[nn4+1][c] = v.y; sA[nn4+2][c] = v.z; sA[nn4+3][c] = v.w;
  }
  __syncthreads();
  int nn = t & 63, chunk = t >> 6;                 // 64 channels per thread
  u16* dst = feat2Tb + ((size_t)b*N2_ + n0 + nn)*C2_ + chunk*64;
  #pragma unroll
  for (int g = 0; g < 8; ++g) {
    u16 h8[8];
    #pragma unroll
    for (int j = 0; j < 8; ++j) h8[j] = f2bf(sA[nn][chunk*64 + g*8 + j]);
    *(uint4*)(dst + g*8) = pack8(h8);
  }
}

// ---------------- K2a: feat1 transpose -> xcatT kt 0..3 ----------------
__global__ __launch_bounds__(256) void prep1_kernel(
    const float* __restrict__ feat1, u16* __restrict__ xcatT)
{
  __shared__ float sA[64][133];
  int b = blockIdx.y;
  int n0 = blockIdx.x * 64;
  int t = threadIdx.x;
  #pragma unroll
  for (int j = 0; j < 8; ++j) {
    int flat4 = t + j * 256;                       // 2048 float4s: 128c x 64n
    int c = flat4 >> 4, nn4 = (flat4 & 15) * 4;
    float4 v = *(const float4*)(feat1 + ((size_t)b*C1_ + c)*N1_ + n0 + nn4);
    sA[nn4+0][c] = v.x; sA[nn4+1][c] = v.y; sA[nn4+2][c] = v.z; sA[nn4+3][c] = v.w;
  }
  __syncthreads();
  int nn = t & 63, chunk = t >> 6;
  int n = n0 + nn, nt = n >> 4, col = n & 15;
  u16* tb = xcatT + ((size_t)b*256 + nt)*12*512;
  #pragma unroll
  for (int g = 0; g < 4; ++g) {
    int c0 = chunk*32 + g*8;
    u16 h8[8];
    #pragma unroll
    for (int j = 0; j < 8; ++j) h8[j] = f2bf(sA[nn][c0 + j]);
    // c0 channels: kt = c0>>5 = chunk, quad = (c0>>3)&3 = g
    *(uint4*)(tb + (size_t)chunk*512 + (g*16 + col)*8) = pack8(h8);
  }
}

// ---------------- K2b: 3NN interpolate (bf16 gather) -> xcatT kt 4..11 ----------------
// 32 lanes per point: lane seg s reads channels [s*8, s*8+8) of each of the 3
// neighbor rows (contiguous 512B per row across the 32 lanes).
__global__ __launch_bounds__(256) void interp2_kernel(
    const u16* __restrict__ feat2Tb, const int* __restrict__ idx_in,
    const float* __restrict__ w_in, u16* __restrict__ xcatT)
{
  int b = blockIdx.y;
  int p0 = blockIdx.x * 64;                        // 64 points per block
  int t = threadIdx.x;
  int seg = t & 31;                                // 8-channel segment
  int pl  = t >> 5;                                // 8 points per pass
  #pragma unroll 2
  for (int pass = 0; pass < 8; ++pass) {
    int n = p0 + pass*8 + pl;
    int base = b*N1_ + n;
    int i0 = idx_in[base], i1 = idx_in[base + 65536], i2 = idx_in[base + 131072];
    float w0 = w_in[base], w1 = w_in[base + 65536], w2 = w_in[base + 131072];
    const u16* fb = feat2Tb + (size_t)b*N2_*C2_ + seg*8;
    U128 a, c, d;
    a.u = *(const uint4*)(fb + (size_t)i0*C2_);
    c.u = *(const uint4*)(fb + (size_t)i1*C2_);
    d.u = *(const uint4*)(fb + (size_t)i2*C2_);
    u16 h8[8];
    #pragma unroll
    for (int j = 0; j < 8; ++j)
      h8[j] = f2bf(w0*bf2f(a.s[j]) + w1*bf2f(c.s[j]) + w2*bf2f(d.s[j]));
    // output channel cx = 128 + seg*8: kt = 4 + (seg>>2), quad = seg&3
    int nt = n >> 4, col = n & 15;
    int kt = 4 + (seg >> 2), quad = seg & 3;
    *(uint4*)(xcatT + (((size_t)b*256 + nt)*12 + kt)*512 + (quad*16 + col)*8) = pack8(h8);
  }
}

// ---------------- K3: GEMM1 MFMA, per-block partial stats (NO global atomics) ----------------
__global__ __launch_bounds__(256) void gemm1_mfma(
    const u16* __restrict__ xcatT, const u16* __restrict__ w0b,
    const float* __restrict__ b0p, u16* __restrict__ y0T,
    float* __restrict__ p0)
{
  __shared__ float ps[4][64][2];                   // [wave][ch64][sum|sq]
  int t = threadIdx.x;
  int wave = t >> 6, lane = t & 63;
  int col = lane & 15, quad = lane >> 4;
  int wm = wave >> 1, wn = wave & 1;
  int b = blockIdx.y;
  int mtb = blockIdx.z*8 + wm*4;
  int ntb = blockIdx.x*8 + wn*4;

  const u16* ap = w0b + lane*8;
  const u16* bp = xcatT + ((size_t)(b*256 + ntb)*12)*512 + lane*8;

  floatx4 acc[4][4] = {};
  bf16x8 af[4], bf[4], afn[4], bfn[4];
  #pragma unroll
  for (int i = 0; i < 4; ++i) {
    af[i] = ldfrag(ap + (size_t)((mtb+i)*12)*512);
    bf[i] = ldfrag(bp + (size_t)(i*12)*512);
  }
  #pragma unroll 1
  for (int kt = 1; kt < 12; ++kt) {
    #pragma unroll
    for (int i = 0; i < 4; ++i) afn[i] = ldfrag(ap + (size_t)((mtb+i)*12 + kt)*512);
    #pragma unroll
    for (int i = 0; i < 4; ++i) bfn[i] = ldfrag(bp + (size_t)(i*12 + kt)*512);
    #pragma unroll
    for (int mt = 0; mt < 4; ++mt)
      #pragma unroll
      for (int nt = 0; nt < 4; ++nt)
        acc[mt][nt] = __builtin_amdgcn_mfma_f32_16x16x32_bf16(af[mt], bf[nt], acc[mt][nt], 0, 0, 0);
    #pragma unroll
    for (int i = 0; i < 4; ++i) { af[i] = afn[i]; bf[i] = bfn[i]; }
  }
  #pragma unroll
  for (int mt = 0; mt < 4; ++mt)
    #pragma unroll
    for (int nt = 0; nt < 4; ++nt)
      acc[mt][nt] = __builtin_amdgcn_mfma_f32_16x16x32_bf16(af[mt], bf[nt], acc[mt][nt], 0, 0, 0);

  int m0 = blockIdx.z*128 + wm*64;
  #pragma unroll
  for (int mt = 0; mt < 4; ++mt) {
    float4 bias4 = *(const float4*)(b0p + m0 + mt*16 + quad*4);
    float bia[4] = {bias4.x, bias4.y, bias4.z, bias4.w};
    int kt_out = (m0 >> 5) + (mt >> 1);
    int quad_out = ((mt & 1) << 1) | (quad >> 1);
    int j0 = (quad & 1) * 4;
    float s[4] = {}, q[4] = {};
    #pragma unroll
    for (int nt = 0; nt < 4; ++nt) {
      int nt_g = ntb + nt;
      u16 h[4];
      #pragma unroll
      for (int r = 0; r < 4; ++r) {
        float v = acc[mt][nt][r] + bia[r];
        u16 hh = f2bf(v);
        float vr = bf2f(hh);
        h[r] = hh; s[r] += vr; q[r] += vr*vr;
      }
      *(ushort4*)(y0T + (((size_t)b*256 + nt_g)*8 + kt_out)*512 + (quad_out*16 + col)*8 + j0)
          = make_ushort4(h[0], h[1], h[2], h[3]);
    }
    #pragma unroll
    for (int r = 0; r < 4; ++r) {
      float ss = s[r], qq = q[r];
      #pragma unroll
      for (int msk = 1; msk < 16; msk <<= 1) { ss += __shfl_xor(ss, msk); qq += __shfl_xor(qq, msk); }
      if (col == 0) {
        ps[wave][mt*16 + quad*4 + r][0] = ss;
        ps[wave][mt*16 + quad*4 + r][1] = qq;
      }
    }
  }
  __syncthreads();
  {
    int c = t >> 1, k = t & 1;                     // c in [0,128)
    int wbase = (c >> 6) * 2, ch = c & 63;
    float v = ps[wbase][ch][k] + ps[wbase+1][ch][k];
    size_t l = (size_t)blockIdx.z*512 + blockIdx.y*32 + blockIdx.x;
    p0[l*256 + t] = v;
  }
}

// ---------------- K3.5: finalize stats -> scale/shift per channel ----------------
__global__ __launch_bounds__(256) void stats_kernel(
    const float* __restrict__ p, const float* __restrict__ g,
    const float* __restrict__ be, float* __restrict__ scale,
    float* __restrict__ shift, int half_split)
{
  int c = blockIdx.x, t = threadIdx.x;
  size_t base = half_split ? ((size_t)(c >> 7) * 512 * 256 + (size_t)(c & 127) * 2)
                           : ((size_t)c * 2);
  float s = 0.f, q = 0.f;
  #pragma unroll
  for (int i = 0; i < 2; ++i) {
    float2 v = *(const float2*)(p + base + (size_t)(t + i*256) * 256);
    s += v.x; q += v.y;
  }
  #pragma unroll
  for (int m = 1; m < 64; m <<= 1) { s += __shfl_xor(s, m); q += __shfl_xor(q, m); }
  __shared__ float2 red[4];
  if ((t & 63) == 0) red[t >> 6] = make_float2(s, q);
  __syncthreads();
  if (t == 0) {
    float ss = red[0].x + red[1].x + red[2].x + red[3].x;
    float qq = red[0].y + red[1].y + red[2].y + red[3].y;
    float mu  = ss * (1.f/65536.f);
    float var = qq * (1.f/65536.f) - mu*mu;
    float a = g[c] * rsqrtf(var + 1e-5f);
    scale[c] = a; shift[c] = be[c] - mu*a;
  }
}

// ---------------- K4: GEMM2 MFMA, BN0+ReLU fused on B-load, partial stats ----------------
__global__ __launch_bounds__(256) void gemm2_mfma(
    const u16* __restrict__ y0T, const u16* __restrict__ w1b,
    const float* __restrict__ b1p,
    const float* __restrict__ scale0, const float* __restrict__ shift0,
    float* __restrict__ out, float* __restrict__ p1)
{
  __shared__ float a0s[CM_], bb0s[CM_];
  __shared__ float ps[4][64][2];
  int t = threadIdx.x;
  a0s[t] = scale0[t]; bb0s[t] = shift0[t];
  __syncthreads();
  int wave = t >> 6, lane = t & 63;
  int col = lane & 15, quad = lane >> 4;
  int wm = wave >> 1, wn = wave & 1;
  int b = blockIdx.y;
  int mtb = wm*4;
  int ntb = blockIdx.x*8 + wn*4;

  const u16* ap = w1b + lane*8;
  const u16* bp = y0T + ((size_t)(b*256 + ntb)*8)*512 + lane*8;

  floatx4 acc[4][4] = {};
  bf16x8 af[4], afn[4];
  U128 braw[4], brawn[4];
  #pragma unroll
  for (int i = 0; i < 4; ++i) {
    af[i] = ldfrag(ap + (size_t)((mtb+i)*8)*512);
    braw[i].u = *(const uint4*)(bp + (size_t)(i*8)*512);
  }
  #pragma unroll 1
  for (int kt = 1; kt < 8; ++kt) {
    #pragma unroll
    for (int i = 0; i < 4; ++i) afn[i] = ldfrag(ap + (size_t)((mtb+i)*8 + kt)*512);
    #pragma unroll
    for (int i = 0; i < 4; ++i) brawn[i].u = *(const uint4*)(bp + (size_t)(i*8 + kt)*512);
    int c0 = (kt-1)*32 + quad*8;
    float4 av0 = *(const float4*)&a0s[c0], av1 = *(const float4*)&a0s[c0+4];
    float4 bv0 = *(const float4*)&bb0s[c0], bv1 = *(const float4*)&bb0s[c0+4];
    float av[8] = {av0.x,av0.y,av0.z,av0.w,av1.x,av1.y,av1.z,av1.w};
    float bv[8] = {bv0.x,bv0.y,bv0.z,bv0.w,bv1.x,bv1.y,bv1.z,bv1.w};
    bf16x8 bfv[4];
    #pragma unroll
    for (int i = 0; i < 4; ++i) {
      u16 h8[8];
      #pragma unroll
      for (int j = 0; j < 8; ++j)
        h8[j] = f2bf(fmaxf(fmaf(bf2f(braw[i].s[j]), av[j], bv[j]), 0.f));
      U128 x; x.u = pack8(h8); bfv[i] = x.v;
    }
    #pragma unroll
    for (int mt = 0; mt < 4; ++mt)
      #pragma unroll
      for (int nt = 0; nt < 4; ++nt)
        acc[mt][nt] = __builtin_amdgcn_mfma_f32_16x16x32_bf16(af[mt], bfv[nt], acc[mt][nt], 0, 0, 0);
    #pragma unroll
    for (int i = 0; i < 4; ++i) { af[i] = afn[i]; braw[i] = brawn[i]; }
  }
  {
    int c0 = 7*32 + quad*8;
    float4 av0 = *(const float4*)&a0s[c0], av1 = *(const float4*)&a0s[c0+4];
    float4 bv0 = *(const float4*)&bb0s[c0], bv1 = *(const float4*)&bb0s[c0+4];
    float av[8] = {av0.x,av0.y,av0.z,av0.w,av1.x,av1.y,av1.z,av1.w};
    float bv[8] = {bv0.x,bv0.y,bv0.z,bv0.w,bv1.x,bv1.y,bv1.z,bv1.w};
    bf16x8 bfv[4];
    #pragma unroll
    for (int i = 0; i < 4; ++i) {
      u16 h8[8];
      #pragma unroll
      for (int j = 0; j < 8; ++j)
        h8[j] = f2bf(fmaxf(fmaf(bf2f(braw[i].s[j]), av[j], bv[j]), 0.f));
      U128 x; x.u = pack8(h8); bfv[i] = x.v;
    }
    #pragma unroll
    for (int mt = 0; mt < 4; ++mt)
      #pragma unroll
      for (int nt = 0; nt < 4; ++nt)
        acc[mt][nt] = __builtin_amdgcn_mfma_f32_16x16x32_bf16(af[mt], bfv[nt], acc[mt][nt], 0, 0, 0);
  }

  int m0 = wm*64;
  int n0 = blockIdx.x*128 + wn*64;
  #pragma unroll
  for (int mt = 0; mt < 4; ++mt) {
    float4 bias4 = *(const float4*)(b1p + m0 + mt*16 + quad*4);
    float bia[4] = {bias4.x, bias4.y, bias4.z, bias4.w};
    float s[4] = {}, q[4] = {};
    #pragma unroll
    for (int nt = 0; nt < 4; ++nt) {
      int n = n0 + nt*16 + col;
      #pragma unroll
      for (int r = 0; r < 4; ++r) {
        float v = acc[mt][nt][r] + bia[r];
        out[((size_t)b*CO_ + m0 + mt*16 + quad*4 + r)*N1_ + n] = v;
        s[r] += v; q[r] += v*v;
      }
    }
    #pragma unroll
    for (int r = 0; r < 4; ++r) {
      float ss = s[r], qq = q[r];
      #pragma unroll
      for (int msk = 1; msk < 16; msk <<= 1) { ss += __shfl_xor(ss, msk); qq += __shfl_xor(qq, msk); }
      if (col == 0) {
        ps[wave][mt*16 + quad*4 + r][0] = ss;
        ps[wave][mt*16 + quad*4 + r][1] = qq;
      }
    }
  }
  __syncthreads();
  {
    int c = t >> 1, k = t & 1;
    int wbase = (c >> 6) * 2, ch = c & 63;
    float v = ps[wbase][ch][k] + ps[wbase+1][ch][k];
    size_t l = (size_t)blockIdx.y*32 + blockIdx.x;
    p1[l*256 + t] = v;
  }
}

// ---------------- K5: BN1 + ReLU in place on d_out ----------------
__global__ __launch_bounds__(256) void bnrelu_kernel(
    float* __restrict__ out, const float* __restrict__ scale1, const float* __restrict__ shift1)
{
  int idx = blockIdx.x * 256 + threadIdx.x;   // float4 index
  int c = (idx >> 10) & (CO_ - 1);
  float a = scale1[c];
  float bb = shift1[c];
  float4 v = ((const float4*)out)[idx];
  v.x = fmaxf(fmaf(v.x, a, bb), 0.f);
  v.y = fmaxf(fmaf(v.y, a, bb), 0.f);
  v.z = fmaxf(fmaf(v.z, a, bb), 0.f);
  v.w = fmaxf(fmaf(v.w, a, bb), 0.f);
  ((float4*)out)[idx] = v;
}

extern "C" void kernel_launch(void* const* d_in, const int* in_sizes, int n_in,
                              void* d_out, int out_size, void* d_ws, size_t ws_size,
                              hipStream_t stream)
{
  const float* xyz1  = (const float*)d_in[0];
  const float* xyz2  = (const float*)d_in[1];
  const float* feat1 = (const float*)d_in[2];
  const float* feat2 = (const float*)d_in[3];
  const float* w0    = (const float*)d_in[4];
  const float* b0    = (const float*)d_in[5];
  const float* g0    = (const float*)d_in[6];
  const float* be0   = (const float*)d_in[7];
  const float* w1    = (const float*)d_in[8];
  const float* b1    = (const float*)d_in[9];
  const float* g1    = (const float*)d_in[10];
  const float* be1   = (const float*)d_in[11];
  float* out = (float*)d_out;
  char* ws = (char*)d_ws;

  // workspace layout (bytes)
  u16*   xcatT   = (u16*)ws;                                   // 50331648
  float* knn_pd  = (float*)ws;                                 // 3 MB (alias xcatT; dead before prep)
  int*   knn_pi  = (int*)(ws + 3145728);                       // 3 MB
  u16*   y0T     = (u16*)(ws + 50331648);                      // 33554432
  u16*   feat2Tb = (u16*)(ws + 50331648);                      // 8 MB (alias y0T, dead before gemm1)
  u16*   w0b     = (u16*)(ws + 83886080);                      // 196608
  u16*   w1b     = (u16*)(ws + 84082688);                      // 65536
  int*   idx_buf = (int*)(ws + 84148224);                      // 786432
  float* w_buf   = (float*)(ws + 84934656);                    // 786432
  float* p0      = (float*)(ws + 85721088);                    // 1048576
  float* p1      = (float*)(ws + 86769664);                    // 524288
  float* scale0  = (float*)(ws + 87293952);                    // 256
  float* shift0  = scale0 + 256;
  float* scale1  = scale0 + 512;
  float* shift1  = scale0 + 640;

  castw_kernel    <<<64,              256, 0, stream>>>(w0, w1, w0b, w1b);
  knn_part_kernel <<<dim3(16,16,4),   256, 0, stream>>>(xyz1, xyz2, knn_pd, knn_pi);
  knn_merge_kernel<<<256,             256, 0, stream>>>(knn_pd, knn_pi, idx_buf, w_buf);
  tr2_kernel      <<<dim3(16,16),     256, 0, stream>>>(feat2, feat2Tb);
  prep1_kernel    <<<dim3(64,16),     256, 0, stream>>>(feat1, xcatT);
  interp2_kernel  <<<dim3(64,16),     256, 0, stream>>>(feat2Tb, idx_buf, w_buf, xcatT);
  gemm1_mfma      <<<dim3(32,16,2),   256, 0, stream>>>(xcatT, w0b, b0, y0T, p0);
  stats_kernel    <<<256,             256, 0, stream>>>(p0, g0, be0, scale0, shift0, 1);
  gemm2_mfma      <<<dim3(32,16),     256, 0, stream>>>(y0T, w1b, b1, scale0, shift0, out, p1);
  stats_kernel    <<<128,             256, 0, stream>>>(p1, g1, be1, scale1, shift1, 0);
  bnrelu_kernel   <<<8192,            256, 0, stream>>>(out, scale1, shift1);
}